// Round 1
// baseline (964.443 us; speedup 1.0000x reference)
//
#include <hip/hip_runtime.h>
#include <math.h>

#define B_  2
#define L_  2048
#define DM  1024
#define DI  2048
#define DR  64
#define N_  16
#define K_  4
#define NROW (B_*L_)      // 4096
#define CH  64
#define NCH (L_/CH)       // 32

__device__ __forceinline__ float silu_f(float x) { return x / (1.0f + __expf(-x)); }

// ---------------- generic NT GEMM: C[m,n] = sum_k A[m*lda+k]*Bt[n*ldb+k] ----------------
// EPI 0: plain store; EPI 1: v = softplus(v + bias[col])
template<int EPI>
__global__ __launch_bounds__(256)
void gemm_nt(const float* __restrict__ A, int lda,
             const float* __restrict__ Bt, int ldb,
             float* __restrict__ C, int ldc,
             int M, int N, int K, const float* __restrict__ bias)
{
    __shared__ float As[16][68];
    __shared__ float Bs[16][68];
    const int tid = threadIdx.x;
    const int bm = blockIdx.y * 64;
    const int bn = blockIdx.x * 64;
    const int tx = tid & 15, ty = tid >> 4;
    const int lrow = tid >> 2;          // 0..63
    const int lk   = (tid & 3) * 4;     // 0,4,8,12
    float acc[4][4] = {};

    for (int k0 = 0; k0 < K; k0 += 16) {
        float4 av = *(const float4*)(A + (size_t)(bm + lrow) * lda + k0 + lk);
        float4 bv = make_float4(0.f, 0.f, 0.f, 0.f);
        if (bn + lrow < N)
            bv = *(const float4*)(Bt + (size_t)(bn + lrow) * ldb + k0 + lk);
        __syncthreads();
        As[lk+0][lrow] = av.x; As[lk+1][lrow] = av.y; As[lk+2][lrow] = av.z; As[lk+3][lrow] = av.w;
        Bs[lk+0][lrow] = bv.x; Bs[lk+1][lrow] = bv.y; Bs[lk+2][lrow] = bv.z; Bs[lk+3][lrow] = bv.w;
        __syncthreads();
#pragma unroll
        for (int k = 0; k < 16; ++k) {
            const float4 a = *(const float4*)&As[k][ty*4];
            const float4 b = *(const float4*)&Bs[k][tx*4];
            const float ar[4] = {a.x, a.y, a.z, a.w};
            const float br[4] = {b.x, b.y, b.z, b.w};
#pragma unroll
            for (int i = 0; i < 4; ++i)
#pragma unroll
                for (int j = 0; j < 4; ++j)
                    acc[i][j] = fmaf(ar[i], br[j], acc[i][j]);
        }
    }
#pragma unroll
    for (int i = 0; i < 4; ++i) {
        const int row = bm + ty*4 + i;
#pragma unroll
        for (int j = 0; j < 4; ++j) {
            const int col = bn + tx*4 + j;
            if (col < N) {
                float v = acc[i][j];
                if (EPI == 1) {
                    v += bias[col];
                    v = (v > 15.0f) ? v : log1pf(__expf(v));
                }
                C[(size_t)row * ldc + col] = v;
            }
        }
    }
}

// ---------------- causal depthwise conv (K=4) + SiLU ----------------
__global__ __launch_bounds__(256)
void conv_silu_k(const float* __restrict__ xz, const float* __restrict__ cw,
                 const float* __restrict__ cb, float* __restrict__ u)
{
    const size_t idx = (size_t)blockIdx.x * 256 + threadIdx.x;  // over B_*L_*DI
    const int c = (int)(idx & (DI - 1));
    const size_t bl = idx >> 11;           // DI = 2048
    const int l = (int)(bl & (L_ - 1));
    const float4 w = *(const float4*)(cw + (size_t)c * 4);
    const float wk[4] = {w.x, w.y, w.z, w.w};
    float s = cb[c];
#pragma unroll
    for (int k = 0; k < 4; ++k) {
        const int t = l - 3 + k;
        if (t >= 0) s += xz[(bl - 3 + k) * (size_t)(2*DI) + c] * wk[k];
    }
    u[idx] = silu_f(s);
}

// ---------------- selective scan: phase 1 (per-chunk local scan) ----------------
__global__ __launch_bounds__(256)
void scan_phase1(const float* __restrict__ delta, const float* __restrict__ u,
                 const float* __restrict__ dbc, const float* __restrict__ A_log,
                 float* __restrict__ Aprod, float* __restrict__ hfin)
{
    __shared__ float Bs[CH][N_];
    const int tid = threadIdx.x;
    const int d  = blockIdx.x * 256 + tid;
    const int ck = blockIdx.y;
    const int b  = blockIdx.z;
    const int l0 = ck * CH;
    for (int e = tid; e < CH * N_; e += 256) {
        const int lo = e >> 4, n = e & 15;
        Bs[lo][n] = dbc[((size_t)(b*L_ + l0 + lo)) * 96 + 64 + n];
    }
    __syncthreads();
    float An[N_], h[N_], P[N_];
#pragma unroll
    for (int n = 0; n < N_; ++n) {
        An[n] = -__expf(A_log[(size_t)d * N_ + n]);
        h[n] = 0.f; P[n] = 1.f;
    }
    size_t base = ((size_t)(b*L_ + l0)) * DI + d;
    for (int lo = 0; lo < CH; ++lo) {
        const float dl = delta[base];
        const float uu = u[base];
        base += DI;
        const float du = dl * uu;
#pragma unroll
        for (int n = 0; n < N_; ++n) {
            const float da = __expf(dl * An[n]);
            h[n] = fmaf(da, h[n], du * Bs[lo][n]);
            P[n] *= da;
        }
    }
    const size_t o = (((size_t)(b*NCH + ck) * DI) + d) * N_;
#pragma unroll
    for (int n = 0; n < N_; n += 4) {
        *(float4*)(Aprod + o + n) = make_float4(P[n], P[n+1], P[n+2], P[n+3]);
        *(float4*)(hfin  + o + n) = make_float4(h[n], h[n+1], h[n+2], h[n+3]);
    }
}

// ---------------- selective scan: phase 2 (scan over chunks) ----------------
__global__ __launch_bounds__(256)
void scan_phase2(const float* __restrict__ Aprod, const float* __restrict__ hfin,
                 float* __restrict__ hinit)
{
    const size_t idx = (size_t)blockIdx.x * 256 + threadIdx.x;  // over B_*DI*N_
    const int b = (idx >= (size_t)DI * N_) ? 1 : 0;
    const size_t dn = idx - (size_t)b * DI * N_;
    float h = 0.f;
    for (int c = 0; c < NCH; ++c) {
        const size_t o = ((size_t)(b*NCH + c) * DI) * N_ + dn;
        hinit[o] = h;
        h = fmaf(Aprod[o], h, hfin[o]);
    }
}

// ---------------- selective scan: phase 3 (replay + y + gate, writes g into xz[:, :DI]) ----
__global__ __launch_bounds__(256)
void scan_phase3(const float* __restrict__ delta, const float* __restrict__ u,
                 const float* __restrict__ dbc, const float* __restrict__ A_log,
                 const float* __restrict__ hinit, const float* __restrict__ Dp,
                 float* __restrict__ xz)
{
    __shared__ float Bs[CH][N_];
    __shared__ float Cs[CH][N_];
    const int tid = threadIdx.x;
    const int d  = blockIdx.x * 256 + tid;
    const int ck = blockIdx.y;
    const int b  = blockIdx.z;
    const int l0 = ck * CH;
    for (int e = tid; e < CH * N_; e += 256) {
        const int lo = e >> 4, n = e & 15;
        const size_t r = ((size_t)(b*L_ + l0 + lo)) * 96;
        Bs[lo][n] = dbc[r + 64 + n];
        Cs[lo][n] = dbc[r + 80 + n];
    }
    __syncthreads();
    float An[N_], h[N_];
    const size_t ho = (((size_t)(b*NCH + ck) * DI) + d) * N_;
#pragma unroll
    for (int n = 0; n < N_; n += 4) {
        const float4 hv = *(const float4*)(hinit + ho + n);
        h[n] = hv.x; h[n+1] = hv.y; h[n+2] = hv.z; h[n+3] = hv.w;
    }
#pragma unroll
    for (int n = 0; n < N_; ++n)
        An[n] = -__expf(A_log[(size_t)d * N_ + n]);
    const float dp = Dp[d];
    size_t base  = ((size_t)(b*L_ + l0)) * DI + d;
    size_t zbase = ((size_t)(b*L_ + l0)) * (2*DI) + DI + d;
    size_t gbase = ((size_t)(b*L_ + l0)) * (2*DI) + d;
    for (int lo = 0; lo < CH; ++lo) {
        const float dl = delta[base];
        const float uu = u[base];
        base += DI;
        const float du = dl * uu;
        float y = 0.f;
#pragma unroll
        for (int n = 0; n < N_; ++n) {
            const float da = __expf(dl * An[n]);
            h[n] = fmaf(da, h[n], du * Bs[lo][n]);
            y = fmaf(h[n], Cs[lo][n], y);
        }
        y = fmaf(dp, uu, y);
        const float zz = xz[zbase]; zbase += 2*DI;
        xz[gbase] = y * silu_f(zz); gbase += 2*DI;
    }
}

extern "C" void kernel_launch(void* const* d_in, const int* in_sizes, int n_in,
                              void* d_out, int out_size, void* d_ws, size_t ws_size,
                              hipStream_t stream)
{
    const float* x     = (const float*)d_in[0];
    const float* Win   = (const float*)d_in[1];
    const float* cw    = (const float*)d_in[2];
    const float* cb    = (const float*)d_in[3];
    const float* Wx    = (const float*)d_in[4];
    const float* Wdt   = (const float*)d_in[5];
    const float* bdt   = (const float*)d_in[6];
    const float* A_log = (const float*)d_in[7];
    const float* Dp    = (const float*)d_in[8];
    const float* Wout  = (const float*)d_in[9];
    float* out = (float*)d_out;

    float* ws    = (float*)d_ws;
    float* xz    = ws;                                   // NROW * 2*DI
    float* u     = xz    + (size_t)NROW * 2 * DI;        // NROW * DI
    float* delta = u     + (size_t)NROW * DI;            // NROW * DI
    float* dbc   = delta + (size_t)NROW * DI;            // NROW * 96
    float* Aprod = dbc   + (size_t)NROW * 96;            // B_*NCH*DI*N_
    float* hfin  = Aprod + (size_t)B_ * NCH * DI * N_;
    float* hinit = hfin  + (size_t)B_ * NCH * DI * N_;

    const dim3 blk(256);

    // 1) xz = x @ Win^T           (4096 x 4096 x 1024)
    gemm_nt<0><<<dim3(64, 64), blk, 0, stream>>>(x, DM, Win, DM, xz, 2*DI, NROW, 2*DI, DM, nullptr);
    // 2) u = silu(conv1d(xin))
    conv_silu_k<<<dim3((NROW * DI) / 256), blk, 0, stream>>>(xz, cw, cb, u);
    // 3) dbc = u @ Wx^T           (4096 x 96 x 2048)
    gemm_nt<0><<<dim3(2, 64), blk, 0, stream>>>(u, DI, Wx, DI, dbc, 96, NROW, 96, DI, nullptr);
    // 4) delta = softplus(dr @ Wdt^T + bdt)   (4096 x 2048 x 64)
    gemm_nt<1><<<dim3(32, 64), blk, 0, stream>>>(dbc, 96, Wdt, DR, delta, DI, NROW, DI, DR, bdt);
    // 5-7) chunked selective scan
    scan_phase1<<<dim3(DI/256, NCH, B_), blk, 0, stream>>>(delta, u, dbc, A_log, Aprod, hfin);
    scan_phase2<<<dim3((B_*DI*N_)/256), blk, 0, stream>>>(Aprod, hfin, hinit);
    scan_phase3<<<dim3(DI/256, NCH, B_), blk, 0, stream>>>(delta, u, dbc, A_log, hinit, Dp, xz);
    // 8) out = g @ Wout^T         (4096 x 1024 x 2048), g lives in xz[:, :DI]
    gemm_nt<0><<<dim3(16, 64), blk, 0, stream>>>(xz, 2*DI, Wout, DI, out, DM, NROW, DM, DI, nullptr);
}

// Round 2
// 385.154 us; speedup vs baseline: 2.5040x; 2.5040x over previous
//
#include <hip/hip_runtime.h>
#include <math.h>

#define B_  2
#define L_  2048
#define DM  1024
#define DI  2048
#define DR  64
#define N_  16
#define K_  4
#define NROW (B_*L_)      // 4096
#define CH  64
#define NCH (L_/CH)       // 32

typedef __attribute__((ext_vector_type(8))) __bf16 bf16x8;
typedef __attribute__((ext_vector_type(4))) float f32x4;

__device__ __forceinline__ float silu_f(float x) { return x / (1.0f + __expf(-x)); }

__device__ __forceinline__ unsigned short f2bf(float f) {
    unsigned u = __float_as_uint(f);
    unsigned r = (u + 0x7FFF + ((u >> 16) & 1)) >> 16;  // RNE
    return (unsigned short)r;
}

__device__ __forceinline__ void gload_lds16(const void* g, void* l) {
    __builtin_amdgcn_global_load_lds(
        (const __attribute__((address_space(1))) void*)g,
        (__attribute__((address_space(3))) void*)l,
        16, 0, 0);
}

// ---------------- fp32 -> bf16 conversion (8 elems/thread) ----------------
__global__ __launch_bounds__(256)
void f32_to_bf16_k(const float* __restrict__ in, unsigned short* __restrict__ out, int n8)
{
    const int i = blockIdx.x * 256 + threadIdx.x;
    if (i >= n8) return;
    const float4 a = *((const float4*)in + (size_t)i * 2);
    const float4 b = *((const float4*)in + (size_t)i * 2 + 1);
    union { unsigned short s[8]; uint4 v; } o;
    o.s[0] = f2bf(a.x); o.s[1] = f2bf(a.y); o.s[2] = f2bf(a.z); o.s[3] = f2bf(a.w);
    o.s[4] = f2bf(b.x); o.s[5] = f2bf(b.y); o.s[6] = f2bf(b.z); o.s[7] = f2bf(b.w);
    *(uint4*)(out + (size_t)i * 8) = o.v;
}

// ---------------- bf16 MFMA NT GEMM (m97 structure): C = A(MxK) * B(NxK)^T ----------------
// BM=BN=128, BK=32, 256 threads = 4 waves (2x2 of 64x64), 4x4 16x16x32 frags/wave.
// Requires M%128==0, N%128==0, K%32==0.
__global__ __launch_bounds__(256)
void gemm_bf16(const unsigned short* __restrict__ A,
               const unsigned short* __restrict__ B,
               float* __restrict__ C, int ldc, int K)
{
    __shared__ unsigned short As[128 * 32];
    __shared__ unsigned short Bs[128 * 32];
    const int tid = threadIdx.x;
    const int w = tid >> 6;       // wave 0..3
    const int l = tid & 63;
    const int bm = blockIdx.y * 128;
    const int bn = blockIdx.x * 128;
    const int wm = (w >> 1) * 64;
    const int wn = (w & 1) * 64;

    // staging: issue i in {0,1}; wave w covers LDS rows i*64 + w*16 .. +16
    const int srow = w * 16 + (l >> 2);
    const int skel = (l & 3) * 8;
    const unsigned short* a0 = A + (size_t)(bm + srow) * K + skel;
    const unsigned short* a1 = A + (size_t)(bm + 64 + srow) * K + skel;
    const unsigned short* b0 = B + (size_t)(bn + srow) * K + skel;
    const unsigned short* b1 = B + (size_t)(bn + 64 + srow) * K + skel;

    f32x4 acc[4][4] = {};
    const int kk = (l >> 4) * 8;   // fragment k-base
    const int fr = l & 15;         // fragment row/col

    for (int k0 = 0; k0 < K; k0 += 32) {
        gload_lds16(a0 + k0, &As[(w * 16) * 32]);
        gload_lds16(a1 + k0, &As[(64 + w * 16) * 32]);
        gload_lds16(b0 + k0, &Bs[(w * 16) * 32]);
        gload_lds16(b1 + k0, &Bs[(64 + w * 16) * 32]);
        __syncthreads();
        bf16x8 af[4], bfr[4];
#pragma unroll
        for (int i = 0; i < 4; ++i)
            af[i] = *(const bf16x8*)&As[(wm + i * 16 + fr) * 32 + kk];
#pragma unroll
        for (int j = 0; j < 4; ++j)
            bfr[j] = *(const bf16x8*)&Bs[(wn + j * 16 + fr) * 32 + kk];
#pragma unroll
        for (int i = 0; i < 4; ++i)
#pragma unroll
            for (int j = 0; j < 4; ++j)
                acc[i][j] = __builtin_amdgcn_mfma_f32_16x16x32_bf16(af[i], bfr[j], acc[i][j], 0, 0, 0);
        __syncthreads();
    }

    const int fq = l >> 4;
#pragma unroll
    for (int i = 0; i < 4; ++i)
#pragma unroll
        for (int j = 0; j < 4; ++j)
#pragma unroll
            for (int r = 0; r < 4; ++r) {
                const int row = bm + wm + i * 16 + fq * 4 + r;
                const int col = bn + wn + j * 16 + fr;
                C[(size_t)row * ldc + col] = acc[i][j][r];
            }
}

// ---------------- generic fp32 NT GEMM (kept for small GEMMs 2 & 3) ----------------
template<int EPI>
__global__ __launch_bounds__(256)
void gemm_nt(const float* __restrict__ A, int lda,
             const float* __restrict__ Bt, int ldb,
             float* __restrict__ C, int ldc,
             int M, int N, int K, const float* __restrict__ bias)
{
    __shared__ float As[16][68];
    __shared__ float Bs[16][68];
    const int tid = threadIdx.x;
    const int bm = blockIdx.y * 64;
    const int bn = blockIdx.x * 64;
    const int tx = tid & 15, ty = tid >> 4;
    const int lrow = tid >> 2;
    const int lk   = (tid & 3) * 4;
    float acc[4][4] = {};

    for (int k0 = 0; k0 < K; k0 += 16) {
        float4 av = *(const float4*)(A + (size_t)(bm + lrow) * lda + k0 + lk);
        float4 bv = make_float4(0.f, 0.f, 0.f, 0.f);
        if (bn + lrow < N)
            bv = *(const float4*)(Bt + (size_t)(bn + lrow) * ldb + k0 + lk);
        __syncthreads();
        As[lk+0][lrow] = av.x; As[lk+1][lrow] = av.y; As[lk+2][lrow] = av.z; As[lk+3][lrow] = av.w;
        Bs[lk+0][lrow] = bv.x; Bs[lk+1][lrow] = bv.y; Bs[lk+2][lrow] = bv.z; Bs[lk+3][lrow] = bv.w;
        __syncthreads();
#pragma unroll
        for (int k = 0; k < 16; ++k) {
            const float4 a = *(const float4*)&As[k][ty*4];
            const float4 b = *(const float4*)&Bs[k][tx*4];
            const float ar[4] = {a.x, a.y, a.z, a.w};
            const float br[4] = {b.x, b.y, b.z, b.w};
#pragma unroll
            for (int i = 0; i < 4; ++i)
#pragma unroll
                for (int j = 0; j < 4; ++j)
                    acc[i][j] = fmaf(ar[i], br[j], acc[i][j]);
        }
    }
#pragma unroll
    for (int i = 0; i < 4; ++i) {
        const int row = bm + ty*4 + i;
#pragma unroll
        for (int j = 0; j < 4; ++j) {
            const int col = bn + tx*4 + j;
            if (col < N) {
                float v = acc[i][j];
                if (EPI == 1) {
                    v += bias[col];
                    v = (v > 15.0f) ? v : log1pf(__expf(v));
                }
                C[(size_t)row * ldc + col] = v;
            }
        }
    }
}

// ---------------- causal depthwise conv (K=4) + SiLU ----------------
__global__ __launch_bounds__(256)
void conv_silu_k(const float* __restrict__ xz, const float* __restrict__ cw,
                 const float* __restrict__ cb, float* __restrict__ u)
{
    const size_t idx = (size_t)blockIdx.x * 256 + threadIdx.x;
    const int c = (int)(idx & (DI - 1));
    const size_t bl = idx >> 11;
    const int l = (int)(bl & (L_ - 1));
    const float4 w = *(const float4*)(cw + (size_t)c * 4);
    const float wk[4] = {w.x, w.y, w.z, w.w};
    float s = cb[c];
#pragma unroll
    for (int k = 0; k < 4; ++k) {
        const int t = l - 3 + k;
        if (t >= 0) s += xz[(bl - 3 + k) * (size_t)(2*DI) + c] * wk[k];
    }
    u[idx] = silu_f(s);
}

// ---------------- selective scan: phase 1 ----------------
__global__ __launch_bounds__(256)
void scan_phase1(const float* __restrict__ delta, const float* __restrict__ u,
                 const float* __restrict__ dbc, const float* __restrict__ A_log,
                 float* __restrict__ Aprod, float* __restrict__ hfin)
{
    __shared__ float Bs[CH][N_];
    const int tid = threadIdx.x;
    const int d  = blockIdx.x * 256 + tid;
    const int ck = blockIdx.y;
    const int b  = blockIdx.z;
    const int l0 = ck * CH;
    for (int e = tid; e < CH * N_; e += 256) {
        const int lo = e >> 4, n = e & 15;
        Bs[lo][n] = dbc[((size_t)(b*L_ + l0 + lo)) * 96 + 64 + n];
    }
    __syncthreads();
    float An[N_], h[N_], P[N_];
#pragma unroll
    for (int n = 0; n < N_; ++n) {
        An[n] = -__expf(A_log[(size_t)d * N_ + n]);
        h[n] = 0.f; P[n] = 1.f;
    }
    size_t base = ((size_t)(b*L_ + l0)) * DI + d;
    for (int lo = 0; lo < CH; ++lo) {
        const float dl = delta[base];
        const float uu = u[base];
        base += DI;
        const float du = dl * uu;
#pragma unroll
        for (int n = 0; n < N_; ++n) {
            const float da = __expf(dl * An[n]);
            h[n] = fmaf(da, h[n], du * Bs[lo][n]);
            P[n] *= da;
        }
    }
    const size_t o = (((size_t)(b*NCH + ck) * DI) + d) * N_;
#pragma unroll
    for (int n = 0; n < N_; n += 4) {
        *(float4*)(Aprod + o + n) = make_float4(P[n], P[n+1], P[n+2], P[n+3]);
        *(float4*)(hfin  + o + n) = make_float4(h[n], h[n+1], h[n+2], h[n+3]);
    }
}

// ---------------- selective scan: phase 2 ----------------
__global__ __launch_bounds__(256)
void scan_phase2(const float* __restrict__ Aprod, const float* __restrict__ hfin,
                 float* __restrict__ hinit)
{
    const size_t idx = (size_t)blockIdx.x * 256 + threadIdx.x;
    const int b = (idx >= (size_t)DI * N_) ? 1 : 0;
    const size_t dn = idx - (size_t)b * DI * N_;
    float h = 0.f;
    for (int c = 0; c < NCH; ++c) {
        const size_t o = ((size_t)(b*NCH + c) * DI) * N_ + dn;
        hinit[o] = h;
        h = fmaf(Aprod[o], h, hfin[o]);
    }
}

// ---------------- selective scan: phase 3 (replay + y + gate -> bf16 g) ----------------
__global__ __launch_bounds__(256)
void scan_phase3(const float* __restrict__ delta, const float* __restrict__ u,
                 const float* __restrict__ dbc, const float* __restrict__ A_log,
                 const float* __restrict__ hinit, const float* __restrict__ Dp,
                 const float* __restrict__ xz, unsigned short* __restrict__ gb)
{
    __shared__ float Bs[CH][N_];
    __shared__ float Cs[CH][N_];
    const int tid = threadIdx.x;
    const int d  = blockIdx.x * 256 + tid;
    const int ck = blockIdx.y;
    const int b  = blockIdx.z;
    const int l0 = ck * CH;
    for (int e = tid; e < CH * N_; e += 256) {
        const int lo = e >> 4, n = e & 15;
        const size_t r = ((size_t)(b*L_ + l0 + lo)) * 96;
        Bs[lo][n] = dbc[r + 64 + n];
        Cs[lo][n] = dbc[r + 80 + n];
    }
    __syncthreads();
    float An[N_], h[N_];
    const size_t ho = (((size_t)(b*NCH + ck) * DI) + d) * N_;
#pragma unroll
    for (int n = 0; n < N_; n += 4) {
        const float4 hv = *(const float4*)(hinit + ho + n);
        h[n] = hv.x; h[n+1] = hv.y; h[n+2] = hv.z; h[n+3] = hv.w;
    }
#pragma unroll
    for (int n = 0; n < N_; ++n)
        An[n] = -__expf(A_log[(size_t)d * N_ + n]);
    const float dp = Dp[d];
    size_t base  = ((size_t)(b*L_ + l0)) * DI + d;
    size_t zbase = ((size_t)(b*L_ + l0)) * (2*DI) + DI + d;
    size_t gidx  = ((size_t)(b*L_ + l0)) * DI + d;
    for (int lo = 0; lo < CH; ++lo) {
        const float dl = delta[base];
        const float uu = u[base];
        base += DI;
        const float du = dl * uu;
        float y = 0.f;
#pragma unroll
        for (int n = 0; n < N_; ++n) {
            const float da = __expf(dl * An[n]);
            h[n] = fmaf(da, h[n], du * Bs[lo][n]);
            y = fmaf(h[n], Cs[lo][n], y);
        }
        y = fmaf(dp, uu, y);
        const float zz = xz[zbase]; zbase += 2*DI;
        gb[gidx] = f2bf(y * silu_f(zz)); gidx += DI;
    }
}

extern "C" void kernel_launch(void* const* d_in, const int* in_sizes, int n_in,
                              void* d_out, int out_size, void* d_ws, size_t ws_size,
                              hipStream_t stream)
{
    const float* x     = (const float*)d_in[0];
    const float* Win   = (const float*)d_in[1];
    const float* cw    = (const float*)d_in[2];
    const float* cb    = (const float*)d_in[3];
    const float* Wx    = (const float*)d_in[4];
    const float* Wdt   = (const float*)d_in[5];
    const float* bdt   = (const float*)d_in[6];
    const float* A_log = (const float*)d_in[7];
    const float* Dp    = (const float*)d_in[8];
    const float* Wout  = (const float*)d_in[9];
    float* out = (float*)d_out;

    float* ws    = (float*)d_ws;
    float* xz    = ws;                                   // NROW * 2*DI
    float* u     = xz    + (size_t)NROW * 2 * DI;        // NROW * DI
    float* delta = u     + (size_t)NROW * DI;            // NROW * DI
    float* dbc   = delta + (size_t)NROW * DI;            // NROW * 96
    float* Aprod = dbc   + (size_t)NROW * 96;            // B_*NCH*DI*N_
    float* hfin  = Aprod + (size_t)B_ * NCH * DI * N_;
    float* hinit = hfin  + (size_t)B_ * NCH * DI * N_;
    unsigned short* xb  = (unsigned short*)(hinit + (size_t)B_ * NCH * DI * N_);
    unsigned short* wb  = xb  + (size_t)NROW * DM;       // Win bf16: (2*DI) x DM
    unsigned short* wob = wb  + (size_t)(2*DI) * DM;     // Wout bf16: DM x DI
    unsigned short* gb  = wob + (size_t)DM * DI;         // g bf16: NROW x DI

    const dim3 blk(256);

    // 0) fp32 -> bf16 conversions
    f32_to_bf16_k<<<dim3((NROW*DM)/8/256), blk, 0, stream>>>(x,    xb,  (NROW*DM)/8);
    f32_to_bf16_k<<<dim3((2*DI*DM)/8/256), blk, 0, stream>>>(Win,  wb,  (2*DI*DM)/8);
    f32_to_bf16_k<<<dim3((DM*DI)/8/256),   blk, 0, stream>>>(Wout, wob, (DM*DI)/8);
    // 1) xz = x @ Win^T   (4096 x 4096 x 1024, bf16 MFMA)
    gemm_bf16<<<dim3((2*DI)/128, NROW/128), blk, 0, stream>>>(xb, wb, xz, 2*DI, DM);
    // 2) u = silu(conv1d(xin))
    conv_silu_k<<<dim3((NROW * DI) / 256), blk, 0, stream>>>(xz, cw, cb, u);
    // 3) dbc = u @ Wx^T   (4096 x 96 x 2048, fp32)
    gemm_nt<0><<<dim3(2, 64), blk, 0, stream>>>(u, DI, Wx, DI, dbc, 96, NROW, 96, DI, nullptr);
    // 4) delta = softplus(dr @ Wdt^T + bdt)  (4096 x 2048 x 64, fp32)
    gemm_nt<1><<<dim3(32, 64), blk, 0, stream>>>(dbc, 96, Wdt, DR, delta, DI, NROW, DI, DR, bdt);
    // 5-7) chunked selective scan (phase3 writes bf16 g)
    scan_phase1<<<dim3(DI/256, NCH, B_), blk, 0, stream>>>(delta, u, dbc, A_log, Aprod, hfin);
    scan_phase2<<<dim3((B_*DI*N_)/256), blk, 0, stream>>>(Aprod, hfin, hinit);
    scan_phase3<<<dim3(DI/256, NCH, B_), blk, 0, stream>>>(delta, u, dbc, A_log, hinit, Dp, xz, gb);
    // 8) out = g @ Wout^T  (4096 x 1024 x 2048, bf16 MFMA)
    gemm_bf16<<<dim3(DM/128, NROW/128), blk, 0, stream>>>(gb, wob, out, DM, DI);
}

// Round 3
// 296.848 us; speedup vs baseline: 3.2490x; 1.2975x over previous
//
#include <hip/hip_runtime.h>
#include <math.h>

#define B_  2
#define L_  2048
#define DM  1024
#define DI  2048
#define DR  64
#define N_  16
#define K_  4
#define NROW (B_*L_)      // 4096
#define CH  64
#define NCH (L_/CH)       // 32
#define KS  8             // split-K factor for GEMM2

typedef __attribute__((ext_vector_type(8))) __bf16 bf16x8;
typedef __attribute__((ext_vector_type(4))) float f32x4;
typedef unsigned short ushort_t;

__device__ __forceinline__ float silu_f(float x) { return x / (1.0f + __expf(-x)); }

__device__ __forceinline__ unsigned short f2bf(float f) {
    unsigned u = __float_as_uint(f);
    unsigned r = (u + 0x7FFF + ((u >> 16) & 1)) >> 16;  // RNE
    return (unsigned short)r;
}
__device__ __forceinline__ float bf2f(unsigned short h) {
    return __uint_as_float(((unsigned)h) << 16);
}

__device__ __forceinline__ void gload_lds16(const void* g, void* l) {
    __builtin_amdgcn_global_load_lds(
        (const __attribute__((address_space(1))) void*)g,
        (__attribute__((address_space(3))) void*)l,
        16, 0, 0);
}

// ---------------- fp32 -> bf16 (8 elems/thread) ----------------
__global__ __launch_bounds__(256)
void f32_to_bf16_k(const float* __restrict__ in, unsigned short* __restrict__ out, int n8)
{
    const int i = blockIdx.x * 256 + threadIdx.x;
    if (i >= n8) return;
    const float4 a = *((const float4*)in + (size_t)i * 2);
    const float4 b = *((const float4*)in + (size_t)i * 2 + 1);
    union { unsigned short s[8]; uint4 v; } o;
    o.s[0] = f2bf(a.x); o.s[1] = f2bf(a.y); o.s[2] = f2bf(a.z); o.s[3] = f2bf(a.w);
    o.s[4] = f2bf(b.x); o.s[5] = f2bf(b.y); o.s[6] = f2bf(b.z); o.s[7] = f2bf(b.w);
    *(uint4*)(out + (size_t)i * 8) = o.v;
}

// ---------------- fp32 -> split bf16 (hi + lo), scalar (tiny arrays) ----------------
__global__ __launch_bounds__(256)
void f32_to_bf16_split_k(const float* __restrict__ in,
                         unsigned short* __restrict__ hi,
                         unsigned short* __restrict__ lo, int n)
{
    const int i = blockIdx.x * 256 + threadIdx.x;
    if (i >= n) return;
    const float v = in[i];
    const unsigned short h = f2bf(v);
    hi[i] = h;
    lo[i] = f2bf(v - bf2f(h));
}

// ---------------- bf16 MFMA NT GEMM (m97 structure): C = A(MxK) * B(NxK)^T ----------------
__global__ __launch_bounds__(256)
void gemm_bf16(const unsigned short* __restrict__ A,
               const unsigned short* __restrict__ B,
               float* __restrict__ C, int ldc, int K)
{
    __shared__ unsigned short As[128 * 32];
    __shared__ unsigned short Bs[128 * 32];
    const int tid = threadIdx.x;
    const int w = tid >> 6;
    const int l = tid & 63;
    const int bm = blockIdx.y * 128;
    const int bn = blockIdx.x * 128;
    const int wm = (w >> 1) * 64;
    const int wn = (w & 1) * 64;

    const int srow = w * 16 + (l >> 2);
    const int skel = (l & 3) * 8;
    const unsigned short* a0 = A + (size_t)(bm + srow) * K + skel;
    const unsigned short* a1 = A + (size_t)(bm + 64 + srow) * K + skel;
    const unsigned short* b0 = B + (size_t)(bn + srow) * K + skel;
    const unsigned short* b1 = B + (size_t)(bn + 64 + srow) * K + skel;

    f32x4 acc[4][4] = {};
    const int kk = (l >> 4) * 8;
    const int fr = l & 15;

    for (int k0 = 0; k0 < K; k0 += 32) {
        gload_lds16(a0 + k0, &As[(w * 16) * 32]);
        gload_lds16(a1 + k0, &As[(64 + w * 16) * 32]);
        gload_lds16(b0 + k0, &Bs[(w * 16) * 32]);
        gload_lds16(b1 + k0, &Bs[(64 + w * 16) * 32]);
        __syncthreads();
        bf16x8 af[4], bfr[4];
#pragma unroll
        for (int i = 0; i < 4; ++i)
            af[i] = *(const bf16x8*)&As[(wm + i * 16 + fr) * 32 + kk];
#pragma unroll
        for (int j = 0; j < 4; ++j)
            bfr[j] = *(const bf16x8*)&Bs[(wn + j * 16 + fr) * 32 + kk];
#pragma unroll
        for (int i = 0; i < 4; ++i)
#pragma unroll
            for (int j = 0; j < 4; ++j)
                acc[i][j] = __builtin_amdgcn_mfma_f32_16x16x32_bf16(af[i], bfr[j], acc[i][j], 0, 0, 0);
        __syncthreads();
    }

    const int fq = l >> 4;
#pragma unroll
    for (int i = 0; i < 4; ++i)
#pragma unroll
        for (int j = 0; j < 4; ++j)
#pragma unroll
            for (int r = 0; r < 4; ++r) {
                const int row = bm + wm + i * 16 + fq * 4 + r;
                const int col = bn + wn + j * 16 + fr;
                C[(size_t)row * ldc + col] = acc[i][j][r];
            }
}

// ---------------- GEMM2 split-K: part[ks] += u[64rows x 256k] @ Wx^T (96 cols) --------
// Split-precision: u = uh+ul, Wx = wxh+wxl; 3-term MFMA.
__global__ __launch_bounds__(256)
void gemm2_splitk(const unsigned short* __restrict__ uh, const unsigned short* __restrict__ ul,
                  const unsigned short* __restrict__ wxh, const unsigned short* __restrict__ wxl,
                  float* __restrict__ part)
{
    __shared__ unsigned short Ah[64 * 32], Al[64 * 32];
    __shared__ unsigned short Bh[96 * 32], Bl[96 * 32];
    const int tid = threadIdx.x;
    const int w = tid >> 6, l = tid & 63;
    const int ks = blockIdx.x;
    const int bm = blockIdx.y * 64;
    const int kbase = ks * (DI / KS);      // 256-wide K chunk
    const int srow = l >> 2;
    const int skel = (l & 3) * 8;
    const int kk = (l >> 4) * 8, fr = l & 15, fq = l >> 4;

    f32x4 acc[6] = {};
    for (int k0 = 0; k0 < DI / KS; k0 += 32) {
        const int kg = kbase + k0;
        gload_lds16(uh  + (size_t)(bm + w * 16 + srow) * DI + kg + skel, &Ah[(w * 16) * 32]);
        gload_lds16(ul  + (size_t)(bm + w * 16 + srow) * DI + kg + skel, &Al[(w * 16) * 32]);
        gload_lds16(wxh + (size_t)(w * 16 + srow) * DI + kg + skel, &Bh[(w * 16) * 32]);
        gload_lds16(wxl + (size_t)(w * 16 + srow) * DI + kg + skel, &Bl[(w * 16) * 32]);
        if (w < 2) {
            gload_lds16(wxh + (size_t)(64 + w * 16 + srow) * DI + kg + skel, &Bh[(64 + w * 16) * 32]);
            gload_lds16(wxl + (size_t)(64 + w * 16 + srow) * DI + kg + skel, &Bl[(64 + w * 16) * 32]);
        }
        __syncthreads();
        const bf16x8 ah  = *(const bf16x8*)&Ah[(w * 16 + fr) * 32 + kk];
        const bf16x8 al2 = *(const bf16x8*)&Al[(w * 16 + fr) * 32 + kk];
#pragma unroll
        for (int j = 0; j < 6; ++j) {
            const bf16x8 bh  = *(const bf16x8*)&Bh[(j * 16 + fr) * 32 + kk];
            const bf16x8 bl2 = *(const bf16x8*)&Bl[(j * 16 + fr) * 32 + kk];
            acc[j] = __builtin_amdgcn_mfma_f32_16x16x32_bf16(ah,  bh,  acc[j], 0, 0, 0);
            acc[j] = __builtin_amdgcn_mfma_f32_16x16x32_bf16(ah,  bl2, acc[j], 0, 0, 0);
            acc[j] = __builtin_amdgcn_mfma_f32_16x16x32_bf16(al2, bh,  acc[j], 0, 0, 0);
        }
        __syncthreads();
    }
    float* p = part + (size_t)ks * (NROW * 96);
#pragma unroll
    for (int j = 0; j < 6; ++j)
#pragma unroll
        for (int r = 0; r < 4; ++r)
            p[(size_t)(bm + w * 16 + fq * 4 + r) * 96 + j * 16 + fr] = acc[j][r];
}

// ---------------- GEMM2 reduce: dbc = sum(part), dr -> split bf16 ----------------
__global__ __launch_bounds__(256)
void gemm2_reduce(const float* __restrict__ part, float* __restrict__ dbc,
                  unsigned short* __restrict__ drh, unsigned short* __restrict__ drl)
{
    const int idx = blockIdx.x * 256 + threadIdx.x;     // < NROW*96
    float s = 0.f;
#pragma unroll
    for (int ks = 0; ks < KS; ++ks) s += part[(size_t)ks * (NROW * 96) + idx];
    dbc[idx] = s;
    const int col = idx % 96;
    if (col < DR) {
        const int row = idx / 96;
        const unsigned short h = f2bf(s);
        drh[(size_t)row * DR + col] = h;
        drl[(size_t)row * DR + col] = f2bf(s - bf2f(h));
    }
}

// ---------------- GEMM3: delta = softplus(dr @ Wdt^T + bdt), split precision -------
__global__ __launch_bounds__(256)
void gemm3_delta(const unsigned short* __restrict__ Agh, const unsigned short* __restrict__ Agl,
                 const unsigned short* __restrict__ Bgh, const unsigned short* __restrict__ Bgl,
                 const float* __restrict__ bdt, float* __restrict__ delta)
{
    __shared__ unsigned short Ah[128 * 32], Al[128 * 32];
    __shared__ unsigned short Bh[128 * 32], Bl[128 * 32];
    const int tid = threadIdx.x;
    const int w = tid >> 6, l = tid & 63;
    const int bm = blockIdx.y * 128;
    const int bn = blockIdx.x * 128;
    const int wm = (w >> 1) * 64, wn = (w & 1) * 64;
    const int srow = w * 16 + (l >> 2);
    const int skel = (l & 3) * 8;
    const int kk = (l >> 4) * 8, fr = l & 15, fq = l >> 4;

    f32x4 acc[4][4] = {};
    for (int k0 = 0; k0 < DR; k0 += 32) {
        gload_lds16(Agh + (size_t)(bm + srow) * DR + k0 + skel,      &Ah[(w * 16) * 32]);
        gload_lds16(Agh + (size_t)(bm + 64 + srow) * DR + k0 + skel, &Ah[(64 + w * 16) * 32]);
        gload_lds16(Agl + (size_t)(bm + srow) * DR + k0 + skel,      &Al[(w * 16) * 32]);
        gload_lds16(Agl + (size_t)(bm + 64 + srow) * DR + k0 + skel, &Al[(64 + w * 16) * 32]);
        gload_lds16(Bgh + (size_t)(bn + srow) * DR + k0 + skel,      &Bh[(w * 16) * 32]);
        gload_lds16(Bgh + (size_t)(bn + 64 + srow) * DR + k0 + skel, &Bh[(64 + w * 16) * 32]);
        gload_lds16(Bgl + (size_t)(bn + srow) * DR + k0 + skel,      &Bl[(w * 16) * 32]);
        gload_lds16(Bgl + (size_t)(bn + 64 + srow) * DR + k0 + skel, &Bl[(64 + w * 16) * 32]);
        __syncthreads();
        bf16x8 ah[4], al2[4], bh[4], bl2[4];
#pragma unroll
        for (int i = 0; i < 4; ++i) {
            ah[i]  = *(const bf16x8*)&Ah[(wm + i * 16 + fr) * 32 + kk];
            al2[i] = *(const bf16x8*)&Al[(wm + i * 16 + fr) * 32 + kk];
        }
#pragma unroll
        for (int j = 0; j < 4; ++j) {
            bh[j]  = *(const bf16x8*)&Bh[(wn + j * 16 + fr) * 32 + kk];
            bl2[j] = *(const bf16x8*)&Bl[(wn + j * 16 + fr) * 32 + kk];
        }
#pragma unroll
        for (int i = 0; i < 4; ++i)
#pragma unroll
            for (int j = 0; j < 4; ++j) {
                acc[i][j] = __builtin_amdgcn_mfma_f32_16x16x32_bf16(ah[i],  bh[j],  acc[i][j], 0, 0, 0);
                acc[i][j] = __builtin_amdgcn_mfma_f32_16x16x32_bf16(ah[i],  bl2[j], acc[i][j], 0, 0, 0);
                acc[i][j] = __builtin_amdgcn_mfma_f32_16x16x32_bf16(al2[i], bh[j],  acc[i][j], 0, 0, 0);
            }
        __syncthreads();
    }
#pragma unroll
    for (int i = 0; i < 4; ++i)
#pragma unroll
        for (int j = 0; j < 4; ++j)
#pragma unroll
            for (int r = 0; r < 4; ++r) {
                const int row = bm + wm + i * 16 + fq * 4 + r;
                const int col = bn + wn + j * 16 + fr;
                float v = acc[i][j][r] + bdt[col];
                v = (v > 15.0f) ? v : log1pf(__expf(v));
                delta[(size_t)row * DI + col] = v;
            }
}

// ---------------- causal depthwise conv (K=4) + SiLU -> u split bf16 ----------------
__global__ __launch_bounds__(256)
void conv_silu_k(const float* __restrict__ xz, const float* __restrict__ cw,
                 const float* __restrict__ cb,
                 unsigned short* __restrict__ uh, unsigned short* __restrict__ ul)
{
    const size_t idx = (size_t)blockIdx.x * 256 + threadIdx.x;
    const int c = (int)(idx & (DI - 1));
    const size_t bl = idx >> 11;
    const int l = (int)(bl & (L_ - 1));
    const float4 w = *(const float4*)(cw + (size_t)c * 4);
    const float wk[4] = {w.x, w.y, w.z, w.w};
    float s = cb[c];
#pragma unroll
    for (int k = 0; k < 4; ++k) {
        const int t = l - 3 + k;
        if (t >= 0) s += xz[(bl - 3 + k) * (size_t)(2*DI) + c] * wk[k];
    }
    const float v = silu_f(s);
    const unsigned short h = f2bf(v);
    uh[idx] = h;
    ul[idx] = f2bf(v - bf2f(h));
}

// ---------------- selective scan: phase 1 ----------------
__global__ __launch_bounds__(256)
void scan_phase1(const float* __restrict__ delta,
                 const unsigned short* __restrict__ uh, const unsigned short* __restrict__ ul,
                 const float* __restrict__ dbc, const float* __restrict__ A_log,
                 float* __restrict__ Aprod, float* __restrict__ hfin)
{
    __shared__ float Bs[CH][N_];
    const int tid = threadIdx.x;
    const int d  = blockIdx.x * 256 + tid;
    const int ck = blockIdx.y;
    const int b  = blockIdx.z;
    const int l0 = ck * CH;
    for (int e = tid; e < CH * N_; e += 256) {
        const int lo = e >> 4, n = e & 15;
        Bs[lo][n] = dbc[((size_t)(b*L_ + l0 + lo)) * 96 + 64 + n];
    }
    __syncthreads();
    float An[N_], h[N_], P[N_];
#pragma unroll
    for (int n = 0; n < N_; ++n) {
        An[n] = -__expf(A_log[(size_t)d * N_ + n]);
        h[n] = 0.f; P[n] = 1.f;
    }
    size_t base = ((size_t)(b*L_ + l0)) * DI + d;
    for (int lo = 0; lo < CH; ++lo) {
        const float dl = delta[base];
        const float uu = bf2f(uh[base]) + bf2f(ul[base]);
        base += DI;
        const float du = dl * uu;
#pragma unroll
        for (int n = 0; n < N_; ++n) {
            const float da = __expf(dl * An[n]);
            h[n] = fmaf(da, h[n], du * Bs[lo][n]);
            P[n] *= da;
        }
    }
    const size_t o = (((size_t)(b*NCH + ck) * DI) + d) * N_;
#pragma unroll
    for (int n = 0; n < N_; n += 4) {
        *(float4*)(Aprod + o + n) = make_float4(P[n], P[n+1], P[n+2], P[n+3]);
        *(float4*)(hfin  + o + n) = make_float4(h[n], h[n+1], h[n+2], h[n+3]);
    }
}

// ---------------- selective scan: phase 2 (hinit MAY ALIAS Aprod: load-before-store) ----
__global__ __launch_bounds__(256)
void scan_phase2(const float* Aprod, const float* __restrict__ hfin, float* hinit)
{
    const size_t idx = (size_t)blockIdx.x * 256 + threadIdx.x;
    const int b = (idx >= (size_t)DI * N_) ? 1 : 0;
    const size_t dn = idx - (size_t)b * DI * N_;
    float h = 0.f;
    for (int c = 0; c < NCH; ++c) {
        const size_t o = ((size_t)(b*NCH + c) * DI) * N_ + dn;
        const float a = Aprod[o];
        const float f = hfin[o];
        hinit[o] = h;
        h = fmaf(a, h, f);
    }
}

// ---------------- selective scan: phase 3 (replay + y + gate -> bf16 g) ----------------
__global__ __launch_bounds__(256)
void scan_phase3(const float* __restrict__ delta,
                 const unsigned short* __restrict__ uh, const unsigned short* __restrict__ ul,
                 const float* __restrict__ dbc, const float* __restrict__ A_log,
                 const float* __restrict__ hinit, const float* __restrict__ Dp,
                 const float* __restrict__ xz, unsigned short* __restrict__ gb)
{
    __shared__ float Bs[CH][N_];
    __shared__ float Cs[CH][N_];
    const int tid = threadIdx.x;
    const int d  = blockIdx.x * 256 + tid;
    const int ck = blockIdx.y;
    const int b  = blockIdx.z;
    const int l0 = ck * CH;
    for (int e = tid; e < CH * N_; e += 256) {
        const int lo = e >> 4, n = e & 15;
        const size_t r = ((size_t)(b*L_ + l0 + lo)) * 96;
        Bs[lo][n] = dbc[r + 64 + n];
        Cs[lo][n] = dbc[r + 80 + n];
    }
    __syncthreads();
    float An[N_], h[N_];
    const size_t ho = (((size_t)(b*NCH + ck) * DI) + d) * N_;
#pragma unroll
    for (int n = 0; n < N_; n += 4) {
        const float4 hv = *(const float4*)(hinit + ho + n);
        h[n] = hv.x; h[n+1] = hv.y; h[n+2] = hv.z; h[n+3] = hv.w;
    }
#pragma unroll
    for (int n = 0; n < N_; ++n)
        An[n] = -__expf(A_log[(size_t)d * N_ + n]);
    const float dp = Dp[d];
    size_t base  = ((size_t)(b*L_ + l0)) * DI + d;
    size_t zbase = ((size_t)(b*L_ + l0)) * (2*DI) + DI + d;
    size_t gidx  = ((size_t)(b*L_ + l0)) * DI + d;
    for (int lo = 0; lo < CH; ++lo) {
        const float dl = delta[base];
        const float uu = bf2f(uh[base]) + bf2f(ul[base]);
        base += DI;
        const float du = dl * uu;
        float y = 0.f;
#pragma unroll
        for (int n = 0; n < N_; ++n) {
            const float da = __expf(dl * An[n]);
            h[n] = fmaf(da, h[n], du * Bs[lo][n]);
            y = fmaf(h[n], Cs[lo][n], y);
        }
        y = fmaf(dp, uu, y);
        const float zz = xz[zbase]; zbase += 2*DI;
        gb[gidx] = f2bf(y * silu_f(zz)); gidx += DI;
    }
}

extern "C" void kernel_launch(void* const* d_in, const int* in_sizes, int n_in,
                              void* d_out, int out_size, void* d_ws, size_t ws_size,
                              hipStream_t stream)
{
    const float* x     = (const float*)d_in[0];
    const float* Win   = (const float*)d_in[1];
    const float* cw    = (const float*)d_in[2];
    const float* cb    = (const float*)d_in[3];
    const float* Wx    = (const float*)d_in[4];
    const float* Wdt   = (const float*)d_in[5];
    const float* bdt   = (const float*)d_in[6];
    const float* A_log = (const float*)d_in[7];
    const float* Dp    = (const float*)d_in[8];
    const float* Wout  = (const float*)d_in[9];
    float* out = (float*)d_out;

    float* ws    = (float*)d_ws;
    float* xz    = ws;                                    // NROW*2*DI f32
    float* delta = xz    + (size_t)NROW * 2 * DI;         // NROW*DI f32
    float* dbc   = delta + (size_t)NROW * DI;             // NROW*96 f32
    float* Aprod = dbc   + (size_t)NROW * 96;             // B_*NCH*DI*N_ f32
    float* hfin  = Aprod + (size_t)B_ * NCH * DI * N_;    // B_*NCH*DI*N_ f32
    float* hinit = Aprod;                                 // ALIASES Aprod (phase2 load-before-store)
    unsigned short* uh  = (unsigned short*)(hfin + (size_t)B_ * NCH * DI * N_);  // NROW*DI
    unsigned short* ul  = uh  + (size_t)NROW * DI;
    unsigned short* xb  = ul  + (size_t)NROW * DI;        // NROW*DM (dead after GEMM1)
    unsigned short* wb  = xb  + (size_t)NROW * DM;        // 2DI*DM  (dead after GEMM1)
    unsigned short* wob = wb  + (size_t)(2*DI) * DM;      // DM*DI
    unsigned short* gb  = wob + (size_t)DM * DI;          // NROW*DI
    unsigned short* wxh = gb  + (size_t)NROW * DI;        // 96*DI
    unsigned short* wxl = wxh + (size_t)96 * DI;
    unsigned short* wdh = wxl + (size_t)96 * DI;          // DI*DR
    unsigned short* wdl = wdh + (size_t)DI * DR;
    // split-K partials + dr split reuse the dead xb/wb region (16.8 MB):
    float* part = (float*)xb;                             // KS*NROW*96 f32 = 12.6 MB
    unsigned short* drh = (unsigned short*)(part + (size_t)KS * NROW * 96);  // NROW*DR
    unsigned short* drl = drh + (size_t)NROW * DR;

    const dim3 blk(256);

    // 0) conversions
    f32_to_bf16_k<<<dim3((NROW*DM)/8/256), blk, 0, stream>>>(x,    xb,  (NROW*DM)/8);
    f32_to_bf16_k<<<dim3((2*DI*DM)/8/256), blk, 0, stream>>>(Win,  wb,  (2*DI*DM)/8);
    f32_to_bf16_k<<<dim3((DM*DI)/8/256),   blk, 0, stream>>>(Wout, wob, (DM*DI)/8);
    f32_to_bf16_split_k<<<dim3((96*DI+255)/256),  blk, 0, stream>>>(Wx,  wxh, wxl, 96*DI);
    f32_to_bf16_split_k<<<dim3((DI*DR+255)/256),  blk, 0, stream>>>(Wdt, wdh, wdl, DI*DR);
    // 1) xz = x @ Win^T   (bf16 MFMA)
    gemm_bf16<<<dim3((2*DI)/128, NROW/128), blk, 0, stream>>>(xb, wb, xz, 2*DI, DM);
    // 2) u = silu(conv1d(xin)) -> split bf16
    conv_silu_k<<<dim3((NROW * DI) / 256), blk, 0, stream>>>(xz, cw, cb, uh, ul);
    // 3) dbc = u @ Wx^T   (split-K bf16 MFMA + reduce; part overwrites dead xb/wb)
    gemm2_splitk<<<dim3(KS, NROW/64), blk, 0, stream>>>(uh, ul, wxh, wxl, part);
    gemm2_reduce<<<dim3((NROW*96)/256), blk, 0, stream>>>(part, dbc, drh, drl);
    // 4) delta = softplus(dr @ Wdt^T + bdt)   (split bf16 MFMA)
    gemm3_delta<<<dim3(DI/128, NROW/128), blk, 0, stream>>>(drh, drl, wdh, wdl, bdt, delta);
    // 5-7) chunked selective scan
    scan_phase1<<<dim3(DI/256, NCH, B_), blk, 0, stream>>>(delta, uh, ul, dbc, A_log, Aprod, hfin);
    scan_phase2<<<dim3((B_*DI*N_)/256), blk, 0, stream>>>(Aprod, hfin, hinit);
    scan_phase3<<<dim3(DI/256, NCH, B_), blk, 0, stream>>>(delta, uh, ul, dbc, A_log, hinit, Dp, xz, gb);
    // 8) out = g @ Wout^T  (bf16 MFMA)
    gemm_bf16<<<dim3(DM/128, NROW/128), blk, 0, stream>>>(gb, wob, out, DM, DI);
}

// Round 4
// 273.151 us; speedup vs baseline: 3.5308x; 1.0868x over previous
//
#include <hip/hip_runtime.h>
#include <math.h>

#define B_  2
#define L_  2048
#define DM  1024
#define DI  2048
#define DR  64
#define N_  16
#define K_  4
#define NROW (B_*L_)      // 4096
#define CH  64
#define NCH (L_/CH)       // 32
#define KS  8             // split-K factor for GEMM2

typedef __attribute__((ext_vector_type(8))) __bf16 bf16x8;
typedef __attribute__((ext_vector_type(4))) float f32x4;

__device__ __forceinline__ float silu_f(float x) { return x / (1.0f + __expf(-x)); }

// branch-free softplus from native v_exp_f32 / v_log_f32 only (no log1pf libcall)
__device__ __forceinline__ float softplus_f(float v) {
    return fmaxf(v, 0.0f) + __logf(1.0f + __expf(-fabsf(v)));
}

__device__ __forceinline__ unsigned short f2bf(float f) {
    unsigned u = __float_as_uint(f);
    unsigned r = (u + 0x7FFF + ((u >> 16) & 1)) >> 16;  // RNE
    return (unsigned short)r;
}
__device__ __forceinline__ float bf2f(unsigned short h) {
    return __uint_as_float(((unsigned)h) << 16);
}

__device__ __forceinline__ void gload_lds16(const void* g, void* l) {
    __builtin_amdgcn_global_load_lds(
        (const __attribute__((address_space(1))) void*)g,
        (__attribute__((address_space(3))) void*)l,
        16, 0, 0);
}

// ---------------- fp32 -> bf16 (8 elems/thread) ----------------
__global__ __launch_bounds__(256)
void f32_to_bf16_k(const float* __restrict__ in, unsigned short* __restrict__ out, int n8)
{
    const int i = blockIdx.x * 256 + threadIdx.x;
    if (i >= n8) return;
    const float4 a = *((const float4*)in + (size_t)i * 2);
    const float4 b = *((const float4*)in + (size_t)i * 2 + 1);
    union { unsigned short s[8]; uint4 v; } o;
    o.s[0] = f2bf(a.x); o.s[1] = f2bf(a.y); o.s[2] = f2bf(a.z); o.s[3] = f2bf(a.w);
    o.s[4] = f2bf(b.x); o.s[5] = f2bf(b.y); o.s[6] = f2bf(b.z); o.s[7] = f2bf(b.w);
    *(uint4*)(out + (size_t)i * 8) = o.v;
}

// ---------------- fp32 -> split bf16 (hi + lo) ----------------
__global__ __launch_bounds__(256)
void f32_to_bf16_split_k(const float* __restrict__ in,
                         unsigned short* __restrict__ hi,
                         unsigned short* __restrict__ lo, int n)
{
    const int i = blockIdx.x * 256 + threadIdx.x;
    if (i >= n) return;
    const float v = in[i];
    const unsigned short h = f2bf(v);
    hi[i] = h;
    lo[i] = f2bf(v - bf2f(h));
}

// ---------------- bf16 MFMA NT GEMM (m97 structure): C = A(MxK) * B(NxK)^T ----------------
__global__ __launch_bounds__(256)
void gemm_bf16(const unsigned short* __restrict__ A,
               const unsigned short* __restrict__ B,
               float* __restrict__ C, int ldc, int K)
{
    __shared__ unsigned short As[128 * 32];
    __shared__ unsigned short Bs[128 * 32];
    const int tid = threadIdx.x;
    const int w = tid >> 6;
    const int l = tid & 63;
    const int bm = blockIdx.y * 128;
    const int bn = blockIdx.x * 128;
    const int wm = (w >> 1) * 64;
    const int wn = (w & 1) * 64;

    const int srow = w * 16 + (l >> 2);
    const int skel = (l & 3) * 8;
    const unsigned short* a0 = A + (size_t)(bm + srow) * K + skel;
    const unsigned short* a1 = A + (size_t)(bm + 64 + srow) * K + skel;
    const unsigned short* b0 = B + (size_t)(bn + srow) * K + skel;
    const unsigned short* b1 = B + (size_t)(bn + 64 + srow) * K + skel;

    f32x4 acc[4][4] = {};
    const int kk = (l >> 4) * 8;
    const int fr = l & 15;

    for (int k0 = 0; k0 < K; k0 += 32) {
        gload_lds16(a0 + k0, &As[(w * 16) * 32]);
        gload_lds16(a1 + k0, &As[(64 + w * 16) * 32]);
        gload_lds16(b0 + k0, &Bs[(w * 16) * 32]);
        gload_lds16(b1 + k0, &Bs[(64 + w * 16) * 32]);
        __syncthreads();
        bf16x8 af[4], bfr[4];
#pragma unroll
        for (int i = 0; i < 4; ++i)
            af[i] = *(const bf16x8*)&As[(wm + i * 16 + fr) * 32 + kk];
#pragma unroll
        for (int j = 0; j < 4; ++j)
            bfr[j] = *(const bf16x8*)&Bs[(wn + j * 16 + fr) * 32 + kk];
#pragma unroll
        for (int i = 0; i < 4; ++i)
#pragma unroll
            for (int j = 0; j < 4; ++j)
                acc[i][j] = __builtin_amdgcn_mfma_f32_16x16x32_bf16(af[i], bfr[j], acc[i][j], 0, 0, 0);
        __syncthreads();
    }

    const int fq = l >> 4;
#pragma unroll
    for (int i = 0; i < 4; ++i)
#pragma unroll
        for (int j = 0; j < 4; ++j)
#pragma unroll
            for (int r = 0; r < 4; ++r) {
                const int row = bm + wm + i * 16 + fq * 4 + r;
                const int col = bn + wn + j * 16 + fr;
                C[(size_t)row * ldc + col] = acc[i][j][r];
            }
}

// ---------------- GEMM2 split-K: part[ks] += u[64rows x 256k] @ Wx^T (96 cols) --------
__global__ __launch_bounds__(256)
void gemm2_splitk(const unsigned short* __restrict__ uh, const unsigned short* __restrict__ ul,
                  const unsigned short* __restrict__ wxh, const unsigned short* __restrict__ wxl,
                  float* __restrict__ part)
{
    __shared__ unsigned short Ah[64 * 32], Al[64 * 32];
    __shared__ unsigned short Bh[96 * 32], Bl[96 * 32];
    const int tid = threadIdx.x;
    const int w = tid >> 6, l = tid & 63;
    const int ks = blockIdx.x;
    const int bm = blockIdx.y * 64;
    const int kbase = ks * (DI / KS);
    const int srow = l >> 2;
    const int skel = (l & 3) * 8;
    const int kk = (l >> 4) * 8, fr = l & 15, fq = l >> 4;

    f32x4 acc[6] = {};
    for (int k0 = 0; k0 < DI / KS; k0 += 32) {
        const int kg = kbase + k0;
        gload_lds16(uh  + (size_t)(bm + w * 16 + srow) * DI + kg + skel, &Ah[(w * 16) * 32]);
        gload_lds16(ul  + (size_t)(bm + w * 16 + srow) * DI + kg + skel, &Al[(w * 16) * 32]);
        gload_lds16(wxh + (size_t)(w * 16 + srow) * DI + kg + skel, &Bh[(w * 16) * 32]);
        gload_lds16(wxl + (size_t)(w * 16 + srow) * DI + kg + skel, &Bl[(w * 16) * 32]);
        if (w < 2) {
            gload_lds16(wxh + (size_t)(64 + w * 16 + srow) * DI + kg + skel, &Bh[(64 + w * 16) * 32]);
            gload_lds16(wxl + (size_t)(64 + w * 16 + srow) * DI + kg + skel, &Bl[(64 + w * 16) * 32]);
        }
        __syncthreads();
        const bf16x8 ah  = *(const bf16x8*)&Ah[(w * 16 + fr) * 32 + kk];
        const bf16x8 al2 = *(const bf16x8*)&Al[(w * 16 + fr) * 32 + kk];
#pragma unroll
        for (int j = 0; j < 6; ++j) {
            const bf16x8 bh  = *(const bf16x8*)&Bh[(j * 16 + fr) * 32 + kk];
            const bf16x8 bl2 = *(const bf16x8*)&Bl[(j * 16 + fr) * 32 + kk];
            acc[j] = __builtin_amdgcn_mfma_f32_16x16x32_bf16(ah,  bh,  acc[j], 0, 0, 0);
            acc[j] = __builtin_amdgcn_mfma_f32_16x16x32_bf16(ah,  bl2, acc[j], 0, 0, 0);
            acc[j] = __builtin_amdgcn_mfma_f32_16x16x32_bf16(al2, bh,  acc[j], 0, 0, 0);
        }
        __syncthreads();
    }
    float* p = part + (size_t)ks * (NROW * 96);
#pragma unroll
    for (int j = 0; j < 6; ++j)
#pragma unroll
        for (int r = 0; r < 4; ++r)
            p[(size_t)(bm + w * 16 + fq * 4 + r) * 96 + j * 16 + fr] = acc[j][r];
}

// ---------------- GEMM2 reduce: dbc = sum(part), dr -> split bf16 ----------------
__global__ __launch_bounds__(256)
void gemm2_reduce(const float* __restrict__ part, float* __restrict__ dbc,
                  unsigned short* __restrict__ drh, unsigned short* __restrict__ drl)
{
    const int idx = blockIdx.x * 256 + threadIdx.x;
    float s = 0.f;
#pragma unroll
    for (int ks = 0; ks < KS; ++ks) s += part[(size_t)ks * (NROW * 96) + idx];
    dbc[idx] = s;
    const int col = idx % 96;
    if (col < DR) {
        const int row = idx / 96;
        const unsigned short h = f2bf(s);
        drh[(size_t)row * DR + col] = h;
        drl[(size_t)row * DR + col] = f2bf(s - bf2f(h));
    }
}

// ---------------- GEMM3: delta = softplus(dr @ Wdt^T + bdt), split precision -------
__global__ __launch_bounds__(256)
void gemm3_delta(const unsigned short* __restrict__ Agh, const unsigned short* __restrict__ Agl,
                 const unsigned short* __restrict__ Bgh, const unsigned short* __restrict__ Bgl,
                 const float* __restrict__ bdt, float* __restrict__ delta)
{
    __shared__ unsigned short Ah[128 * 32], Al[128 * 32];
    __shared__ unsigned short Bh[128 * 32], Bl[128 * 32];
    const int tid = threadIdx.x;
    const int w = tid >> 6, l = tid & 63;
    const int bm = blockIdx.y * 128;
    const int bn = blockIdx.x * 128;
    const int wm = (w >> 1) * 64, wn = (w & 1) * 64;
    const int srow = w * 16 + (l >> 2);
    const int skel = (l & 3) * 8;
    const int kk = (l >> 4) * 8, fr = l & 15, fq = l >> 4;

    f32x4 acc[4][4] = {};
    for (int k0 = 0; k0 < DR; k0 += 32) {
        gload_lds16(Agh + (size_t)(bm + srow) * DR + k0 + skel,      &Ah[(w * 16) * 32]);
        gload_lds16(Agh + (size_t)(bm + 64 + srow) * DR + k0 + skel, &Ah[(64 + w * 16) * 32]);
        gload_lds16(Agl + (size_t)(bm + srow) * DR + k0 + skel,      &Al[(w * 16) * 32]);
        gload_lds16(Agl + (size_t)(bm + 64 + srow) * DR + k0 + skel, &Al[(64 + w * 16) * 32]);
        gload_lds16(Bgh + (size_t)(bn + srow) * DR + k0 + skel,      &Bh[(w * 16) * 32]);
        gload_lds16(Bgh + (size_t)(bn + 64 + srow) * DR + k0 + skel, &Bh[(64 + w * 16) * 32]);
        gload_lds16(Bgl + (size_t)(bn + srow) * DR + k0 + skel,      &Bl[(w * 16) * 32]);
        gload_lds16(Bgl + (size_t)(bn + 64 + srow) * DR + k0 + skel, &Bl[(64 + w * 16) * 32]);
        __syncthreads();
        bf16x8 ah[4], al2[4], bh[4], bl2[4];
#pragma unroll
        for (int i = 0; i < 4; ++i) {
            ah[i]  = *(const bf16x8*)&Ah[(wm + i * 16 + fr) * 32 + kk];
            al2[i] = *(const bf16x8*)&Al[(wm + i * 16 + fr) * 32 + kk];
        }
#pragma unroll
        for (int j = 0; j < 4; ++j) {
            bh[j]  = *(const bf16x8*)&Bh[(wn + j * 16 + fr) * 32 + kk];
            bl2[j] = *(const bf16x8*)&Bl[(wn + j * 16 + fr) * 32 + kk];
        }
#pragma unroll
        for (int i = 0; i < 4; ++i)
#pragma unroll
            for (int j = 0; j < 4; ++j) {
                acc[i][j] = __builtin_amdgcn_mfma_f32_16x16x32_bf16(ah[i],  bh[j],  acc[i][j], 0, 0, 0);
                acc[i][j] = __builtin_amdgcn_mfma_f32_16x16x32_bf16(ah[i],  bl2[j], acc[i][j], 0, 0, 0);
                acc[i][j] = __builtin_amdgcn_mfma_f32_16x16x32_bf16(al2[i], bh[j],  acc[i][j], 0, 0, 0);
            }
        __syncthreads();
    }
#pragma unroll
    for (int i = 0; i < 4; ++i)
#pragma unroll
        for (int j = 0; j < 4; ++j)
#pragma unroll
            for (int r = 0; r < 4; ++r) {
                const int row = bm + wm + i * 16 + fq * 4 + r;
                const int col = bn + wn + j * 16 + fr;
                delta[(size_t)row * DI + col] = softplus_f(acc[i][j][r] + bdt[col]);
            }
}

// ---------------- causal depthwise conv (K=4) + SiLU -> u split bf16 ----------------
__global__ __launch_bounds__(256)
void conv_silu_k(const float* __restrict__ xz, const float* __restrict__ cw,
                 const float* __restrict__ cb,
                 unsigned short* __restrict__ uh, unsigned short* __restrict__ ul)
{
    const size_t idx = (size_t)blockIdx.x * 256 + threadIdx.x;
    const int c = (int)(idx & (DI - 1));
    const size_t bl = idx >> 11;
    const int l = (int)(bl & (L_ - 1));
    const float4 w = *(const float4*)(cw + (size_t)c * 4);
    const float wk[4] = {w.x, w.y, w.z, w.w};
    float s = cb[c];
#pragma unroll
    for (int k = 0; k < 4; ++k) {
        const int t = l - 3 + k;
        if (t >= 0) s += xz[(bl - 3 + k) * (size_t)(2*DI) + c] * wk[k];
    }
    const float v = silu_f(s);
    const unsigned short h = f2bf(v);
    uh[idx] = h;
    ul[idx] = f2bf(v - bf2f(h));
}

// ---------------- selective scan: phase 1 ----------------
__global__ __launch_bounds__(256)
void scan_phase1(const float* __restrict__ delta,
                 const unsigned short* __restrict__ uh, const unsigned short* __restrict__ ul,
                 const float* __restrict__ dbc, const float* __restrict__ A_log,
                 float* __restrict__ Aprod, float* __restrict__ hfin)
{
    __shared__ float Bs[CH][N_];
    const int tid = threadIdx.x;
    const int d  = blockIdx.x * 256 + tid;
    const int ck = blockIdx.y;
    const int b  = blockIdx.z;
    const int l0 = ck * CH;
    for (int e = tid; e < CH * N_; e += 256) {
        const int lo = e >> 4, n = e & 15;
        Bs[lo][n] = dbc[((size_t)(b*L_ + l0 + lo)) * 96 + 64 + n];
    }
    __syncthreads();
    float An[N_], h[N_], P[N_];
#pragma unroll
    for (int n = 0; n < N_; ++n) {
        An[n] = -__expf(A_log[(size_t)d * N_ + n]);
        h[n] = 0.f; P[n] = 1.f;
    }
    size_t base = ((size_t)(b*L_ + l0)) * DI + d;
    for (int lo = 0; lo < CH; ++lo) {
        const float dl = delta[base];
        const float uu = bf2f(uh[base]) + bf2f(ul[base]);
        base += DI;
        const float du = dl * uu;
#pragma unroll
        for (int n = 0; n < N_; ++n) {
            const float da = __expf(dl * An[n]);
            h[n] = fmaf(da, h[n], du * Bs[lo][n]);
            P[n] *= da;
        }
    }
    const size_t o = (((size_t)(b*NCH + ck) * DI) + d) * N_;
#pragma unroll
    for (int n = 0; n < N_; n += 4) {
        *(float4*)(Aprod + o + n) = make_float4(P[n], P[n+1], P[n+2], P[n+3]);
        *(float4*)(hfin  + o + n) = make_float4(h[n], h[n+1], h[n+2], h[n+3]);
    }
}

// ---------------- selective scan: phase 2 (hinit MAY ALIAS Aprod: load-before-store) ----
__global__ __launch_bounds__(256)
void scan_phase2(const float* Aprod, const float* __restrict__ hfin, float* hinit)
{
    const size_t idx = (size_t)blockIdx.x * 256 + threadIdx.x;
    const int b = (idx >= (size_t)DI * N_) ? 1 : 0;
    const size_t dn = idx - (size_t)b * DI * N_;
    float h = 0.f;
    for (int c = 0; c < NCH; ++c) {
        const size_t o = ((size_t)(b*NCH + c) * DI) * N_ + dn;
        const float a = Aprod[o];
        const float f = hfin[o];
        hinit[o] = h;
        h = fmaf(a, h, f);
    }
}

// ---------------- selective scan: phase 3 (replay + y + gate -> bf16 g) ----------------
__global__ __launch_bounds__(256)
void scan_phase3(const float* __restrict__ delta,
                 const unsigned short* __restrict__ uh, const unsigned short* __restrict__ ul,
                 const float* __restrict__ dbc, const float* __restrict__ A_log,
                 const float* __restrict__ hinit, const float* __restrict__ Dp,
                 const float* __restrict__ xz, unsigned short* __restrict__ gb)
{
    __shared__ float Bs[CH][N_];
    __shared__ float Cs[CH][N_];
    const int tid = threadIdx.x;
    const int d  = blockIdx.x * 256 + tid;
    const int ck = blockIdx.y;
    const int b  = blockIdx.z;
    const int l0 = ck * CH;
    for (int e = tid; e < CH * N_; e += 256) {
        const int lo = e >> 4, n = e & 15;
        const size_t r = ((size_t)(b*L_ + l0 + lo)) * 96;
        Bs[lo][n] = dbc[r + 64 + n];
        Cs[lo][n] = dbc[r + 80 + n];
    }
    __syncthreads();
    float An[N_], h[N_];
    const size_t ho = (((size_t)(b*NCH + ck) * DI) + d) * N_;
#pragma unroll
    for (int n = 0; n < N_; n += 4) {
        const float4 hv = *(const float4*)(hinit + ho + n);
        h[n] = hv.x; h[n+1] = hv.y; h[n+2] = hv.z; h[n+3] = hv.w;
    }
#pragma unroll
    for (int n = 0; n < N_; ++n)
        An[n] = -__expf(A_log[(size_t)d * N_ + n]);
    const float dp = Dp[d];
    size_t base  = ((size_t)(b*L_ + l0)) * DI + d;
    size_t zbase = ((size_t)(b*L_ + l0)) * (2*DI) + DI + d;
    size_t gidx  = ((size_t)(b*L_ + l0)) * DI + d;
    for (int lo = 0; lo < CH; ++lo) {
        const float dl = delta[base];
        const float uu = bf2f(uh[base]) + bf2f(ul[base]);
        base += DI;
        const float du = dl * uu;
        float y = 0.f;
#pragma unroll
        for (int n = 0; n < N_; ++n) {
            const float da = __expf(dl * An[n]);
            h[n] = fmaf(da, h[n], du * Bs[lo][n]);
            y = fmaf(h[n], Cs[lo][n], y);
        }
        y = fmaf(dp, uu, y);
        const float zz = xz[zbase]; zbase += 2*DI;
        gb[gidx] = f2bf(y * silu_f(zz)); gidx += DI;
    }
}

extern "C" void kernel_launch(void* const* d_in, const int* in_sizes, int n_in,
                              void* d_out, int out_size, void* d_ws, size_t ws_size,
                              hipStream_t stream)
{
    const float* x     = (const float*)d_in[0];
    const float* Win   = (const float*)d_in[1];
    const float* cw    = (const float*)d_in[2];
    const float* cb    = (const float*)d_in[3];
    const float* Wx    = (const float*)d_in[4];
    const float* Wdt   = (const float*)d_in[5];
    const float* bdt   = (const float*)d_in[6];
    const float* A_log = (const float*)d_in[7];
    const float* Dp    = (const float*)d_in[8];
    const float* Wout  = (const float*)d_in[9];
    float* out = (float*)d_out;

    float* ws    = (float*)d_ws;
    float* xz    = ws;                                    // NROW*2*DI f32
    float* delta = xz    + (size_t)NROW * 2 * DI;         // NROW*DI f32
    float* dbc   = delta + (size_t)NROW * DI;             // NROW*96 f32
    float* Aprod = dbc   + (size_t)NROW * 96;             // B_*NCH*DI*N_ f32
    float* hfin  = Aprod + (size_t)B_ * NCH * DI * N_;    // B_*NCH*DI*N_ f32
    float* hinit = Aprod;                                 // ALIASES Aprod (phase2 load-before-store)
    unsigned short* uh  = (unsigned short*)(hfin + (size_t)B_ * NCH * DI * N_);  // NROW*DI
    unsigned short* ul  = uh  + (size_t)NROW * DI;
    unsigned short* xb  = ul  + (size_t)NROW * DI;        // NROW*DM (dead after GEMM1)
    unsigned short* wb  = xb  + (size_t)NROW * DM;        // 2DI*DM  (dead after GEMM1)
    unsigned short* wob = wb  + (size_t)(2*DI) * DM;      // DM*DI
    unsigned short* gb  = wob + (size_t)DM * DI;          // NROW*DI
    unsigned short* wxh = gb  + (size_t)NROW * DI;        // 96*DI
    unsigned short* wxl = wxh + (size_t)96 * DI;
    unsigned short* wdh = wxl + (size_t)96 * DI;          // DI*DR
    unsigned short* wdl = wdh + (size_t)DI * DR;
    float* part = (float*)xb;                             // KS*NROW*96 f32 (dead xb/wb region)
    unsigned short* drh = (unsigned short*)(part + (size_t)KS * NROW * 96);  // NROW*DR
    unsigned short* drl = drh + (size_t)NROW * DR;

    const dim3 blk(256);

    // 0) conversions
    f32_to_bf16_k<<<dim3((NROW*DM)/8/256), blk, 0, stream>>>(x,    xb,  (NROW*DM)/8);
    f32_to_bf16_k<<<dim3((2*DI*DM)/8/256), blk, 0, stream>>>(Win,  wb,  (2*DI*DM)/8);
    f32_to_bf16_k<<<dim3((DM*DI)/8/256),   blk, 0, stream>>>(Wout, wob, (DM*DI)/8);
    f32_to_bf16_split_k<<<dim3((96*DI+255)/256),  blk, 0, stream>>>(Wx,  wxh, wxl, 96*DI);
    f32_to_bf16_split_k<<<dim3((DI*DR+255)/256),  blk, 0, stream>>>(Wdt, wdh, wdl, DI*DR);
    // 1) xz = x @ Win^T   (bf16 MFMA)
    gemm_bf16<<<dim3((2*DI)/128, NROW/128), blk, 0, stream>>>(xb, wb, xz, 2*DI, DM);
    // 2) u = silu(conv1d(xin)) -> split bf16
    conv_silu_k<<<dim3((NROW * DI) / 256), blk, 0, stream>>>(xz, cw, cb, uh, ul);
    // 3) dbc = u @ Wx^T   (split-K bf16 MFMA + reduce)
    gemm2_splitk<<<dim3(KS, NROW/64), blk, 0, stream>>>(uh, ul, wxh, wxl, part);
    gemm2_reduce<<<dim3((NROW*96)/256), blk, 0, stream>>>(part, dbc, drh, drl);
    // 4) delta = softplus(dr @ Wdt^T + bdt)   (split bf16 MFMA)
    gemm3_delta<<<dim3(DI/128, NROW/128), blk, 0, stream>>>(drh, drl, wdh, wdl, bdt, delta);
    // 5-7) chunked selective scan
    scan_phase1<<<dim3(DI/256, NCH, B_), blk, 0, stream>>>(delta, uh, ul, dbc, A_log, Aprod, hfin);
    scan_phase2<<<dim3((B_*DI*N_)/256), blk, 0, stream>>>(Aprod, hfin, hinit);
    scan_phase3<<<dim3(DI/256, NCH, B_), blk, 0, stream>>>(delta, uh, ul, dbc, A_log, hinit, Dp, xz, gb);
    // 8) out = g @ Wout^T  (bf16 MFMA)
    gemm_bf16<<<dim3(DM/128, NROW/128), blk, 0, stream>>>(gb, wob, out, DM, DI);
}

// Round 5
// 263.905 us; speedup vs baseline: 3.6545x; 1.0350x over previous
//
#include <hip/hip_runtime.h>
#include <math.h>

#define B_  2
#define L_  2048
#define DM  1024
#define DI  2048
#define DR  64
#define N_  16
#define K_  4
#define NROW (B_*L_)      // 4096
#define CH  64
#define NCH (L_/CH)       // 32
#define KS  8             // split-K factor for GEMM2

typedef __attribute__((ext_vector_type(8))) __bf16 bf16x8;
typedef __attribute__((ext_vector_type(4))) float f32x4;

__device__ __forceinline__ float silu_f(float x) { return x / (1.0f + __expf(-x)); }

// branch-free softplus from native v_exp_f32 / v_log_f32 only (no log1pf libcall)
__device__ __forceinline__ float softplus_f(float v) {
    return fmaxf(v, 0.0f) + __logf(1.0f + __expf(-fabsf(v)));
}

__device__ __forceinline__ unsigned short f2bf(float f) {
    unsigned u = __float_as_uint(f);
    unsigned r = (u + 0x7FFF + ((u >> 16) & 1)) >> 16;  // RNE
    return (unsigned short)r;
}
__device__ __forceinline__ float bf2f(unsigned short h) {
    return __uint_as_float(((unsigned)h) << 16);
}

__device__ __forceinline__ void gload_lds16(const void* g, void* l) {
    __builtin_amdgcn_global_load_lds(
        (const __attribute__((address_space(1))) void*)g,
        (__attribute__((address_space(3))) void*)l,
        16, 0, 0);
}

// ---------------- fp32 -> bf16 (8 elems/thread) ----------------
__global__ __launch_bounds__(256)
void f32_to_bf16_k(const float* __restrict__ in, unsigned short* __restrict__ out, int n8)
{
    const int i = blockIdx.x * 256 + threadIdx.x;
    if (i >= n8) return;
    const float4 a = *((const float4*)in + (size_t)i * 2);
    const float4 b = *((const float4*)in + (size_t)i * 2 + 1);
    union { unsigned short s[8]; uint4 v; } o;
    o.s[0] = f2bf(a.x); o.s[1] = f2bf(a.y); o.s[2] = f2bf(a.z); o.s[3] = f2bf(a.w);
    o.s[4] = f2bf(b.x); o.s[5] = f2bf(b.y); o.s[6] = f2bf(b.z); o.s[7] = f2bf(b.w);
    *(uint4*)(out + (size_t)i * 8) = o.v;
}

// ---------------- fp32 -> split bf16 (hi + lo) ----------------
__global__ __launch_bounds__(256)
void f32_to_bf16_split_k(const float* __restrict__ in,
                         unsigned short* __restrict__ hi,
                         unsigned short* __restrict__ lo, int n)
{
    const int i = blockIdx.x * 256 + threadIdx.x;
    if (i >= n) return;
    const float v = in[i];
    const unsigned short h = f2bf(v);
    hi[i] = h;
    lo[i] = f2bf(v - bf2f(h));
}

// ============ 256x256 bf16 MFMA NT GEMM, quad-buffered LDS, counted vmcnt ============
// C[MxN] = A[MxK] * B[NxK]^T.  M%256==0, N%256==0, K%32==0, K>=128.
// 512 threads = 8 waves (2M x 4N); per-wave output 128x64 (8x4 16x16 frags).
// LDS 128 KiB: A/B each 4 buffers of 256x32 bf16. Prefetch depth 3 tiles;
// per-iter: vmcnt(8) [never 0 mid-loop], 1 barrier, 12 swizzled ds_read_b128,
// 32 MFMA under setprio, stage tile t+3. Swizzle: slot' = slot ^ ((row>>1)&3),
// applied as inverse-permuted GLOBAL source (linear gload_lds dest) + on read.
__global__ __launch_bounds__(512, 2)
void gemm_bf16_256(const unsigned short* __restrict__ A,
                   const unsigned short* __restrict__ B,
                   float* __restrict__ C, int ldc, int K)
{
    __shared__ unsigned short lds[65536];   // 128 KiB
    const int tid = threadIdx.x;
    const int w = tid >> 6;          // wave 0..7
    const int l = tid & 63;
    const int wM = w >> 2;           // 0..1
    const int wN = w & 3;            // 0..3

    // XCD-aware block swizzle (grid sizes here are multiples of 8)
    const int nbx = gridDim.x;
    const int nwg = nbx * gridDim.y;
    int flat = blockIdx.y * nbx + blockIdx.x;
    flat = (flat & 7) * (nwg >> 3) + (flat >> 3);
    const int bn = (flat % nbx) * 256;
    const int bm = (flat / nbx) * 256;

    // ---- staging addresses (rule 21: linear LDS dest, inverse-swizzled source) ----
    // per issue s: LDS byte o = s*8192 + w*1024 + l*16 -> row = s*128 + w*16 + (l>>2), slot = l&3
    // (row>>1)&3 = (l>>3)&3  (s*128, w*16 contribute 0 mod 4 after >>1)
    const int ksrc = (((l & 3) ^ ((l >> 3) & 3)) * 8);      // element offset in 32-k chunk
    const int srow = w * 16 + (l >> 2);
    const unsigned short* a0 = A + (size_t)(bm + srow) * K + ksrc;
    const unsigned short* a1 = A + (size_t)(bm + 128 + srow) * K + ksrc;
    const unsigned short* b0 = B + (size_t)(bn + srow) * K + ksrc;
    const unsigned short* b1 = B + (size_t)(bn + 128 + srow) * K + ksrc;
    char* ldsc = (char*)lds;

    auto stage = [&](int p, int kof) {   // p = buffer index, kof = element k-offset
        char* d = ldsc + p * 16384 + w * 1024;
        gload_lds16(a0 + kof, d);
        gload_lds16(a1 + kof, d + 8192);
        gload_lds16(b0 + kof, d + 65536);
        gload_lds16(b1 + kof, d + 65536 + 8192);
    };

    // ---- fragment read offsets (elements), swizzled ----
    const int fr = l & 15, fq = l >> 4;
    const int slotr = fq ^ ((fr >> 1) & 3);  // (row>>1)&3 == (fr>>1)&3 for all frag rows
    int aoff[8], boff[4];
#pragma unroll
    for (int i = 0; i < 8; ++i) aoff[i] = (wM * 128 + i * 16 + fr) * 32 + slotr * 8;
#pragma unroll
    for (int j = 0; j < 4; ++j) boff[j] = (wN * 64 + j * 16 + fr) * 32 + slotr * 8;

    f32x4 acc[8][4] = {};
    const int NT = K >> 5;

    // prologue: tiles 0,1,2 in flight (12 loads/thread)
    stage(0, 0);
    stage(1, 32);
    stage(2, 64);

    for (int t = 0; t < NT; ++t) {
        const int rem = NT - 1 - t;
        if (rem >= 2)      asm volatile("s_waitcnt vmcnt(8)" ::: "memory");
        else if (rem == 1) asm volatile("s_waitcnt vmcnt(4)" ::: "memory");
        else               asm volatile("s_waitcnt vmcnt(0)" ::: "memory");
        __builtin_amdgcn_s_barrier();
        __builtin_amdgcn_sched_barrier(0);

        // stage tile t+3 into the buffer freed by tile t-1 (all waves passed barrier)
        if (t + 3 < NT) stage((t + 3) & 3, (t + 3) * 32);

        const unsigned short* Ab = lds + (t & 3) * 8192;
        const unsigned short* Bb = lds + 32768 + (t & 3) * 8192;
        bf16x8 af[8], bf[4];
#pragma unroll
        for (int i = 0; i < 8; ++i) af[i] = *(const bf16x8*)(Ab + aoff[i]);
#pragma unroll
        for (int j = 0; j < 4; ++j) bf[j] = *(const bf16x8*)(Bb + boff[j]);

        __builtin_amdgcn_s_setprio(1);
#pragma unroll
        for (int i = 0; i < 8; ++i)
#pragma unroll
            for (int j = 0; j < 4; ++j)
                acc[i][j] = __builtin_amdgcn_mfma_f32_16x16x32_bf16(af[i], bf[j], acc[i][j], 0, 0, 0);
        __builtin_amdgcn_s_setprio(0);
    }

#pragma unroll
    for (int i = 0; i < 8; ++i)
#pragma unroll
        for (int j = 0; j < 4; ++j)
#pragma unroll
            for (int r = 0; r < 4; ++r) {
                const int row = bm + wM * 128 + i * 16 + fq * 4 + r;
                const int col = bn + wN * 64 + j * 16 + fr;
                C[(size_t)row * ldc + col] = acc[i][j][r];
            }
}

// ---------------- GEMM2 split-K: part[ks] += u[64rows x 256k] @ Wx^T (96 cols) --------
__global__ __launch_bounds__(256)
void gemm2_splitk(const unsigned short* __restrict__ uh, const unsigned short* __restrict__ ul,
                  const unsigned short* __restrict__ wxh, const unsigned short* __restrict__ wxl,
                  float* __restrict__ part)
{
    __shared__ unsigned short Ah[64 * 32], Al[64 * 32];
    __shared__ unsigned short Bh[96 * 32], Bl[96 * 32];
    const int tid = threadIdx.x;
    const int w = tid >> 6, l = tid & 63;
    const int ks = blockIdx.x;
    const int bm = blockIdx.y * 64;
    const int kbase = ks * (DI / KS);
    const int srow = l >> 2;
    const int skel = (l & 3) * 8;
    const int kk = (l >> 4) * 8, fr = l & 15, fq = l >> 4;

    f32x4 acc[6] = {};
    for (int k0 = 0; k0 < DI / KS; k0 += 32) {
        const int kg = kbase + k0;
        gload_lds16(uh  + (size_t)(bm + w * 16 + srow) * DI + kg + skel, &Ah[(w * 16) * 32]);
        gload_lds16(ul  + (size_t)(bm + w * 16 + srow) * DI + kg + skel, &Al[(w * 16) * 32]);
        gload_lds16(wxh + (size_t)(w * 16 + srow) * DI + kg + skel, &Bh[(w * 16) * 32]);
        gload_lds16(wxl + (size_t)(w * 16 + srow) * DI + kg + skel, &Bl[(w * 16) * 32]);
        if (w < 2) {
            gload_lds16(wxh + (size_t)(64 + w * 16 + srow) * DI + kg + skel, &Bh[(64 + w * 16) * 32]);
            gload_lds16(wxl + (size_t)(64 + w * 16 + srow) * DI + kg + skel, &Bl[(64 + w * 16) * 32]);
        }
        __syncthreads();
        const bf16x8 ah  = *(const bf16x8*)&Ah[(w * 16 + fr) * 32 + kk];
        const bf16x8 al2 = *(const bf16x8*)&Al[(w * 16 + fr) * 32 + kk];
#pragma unroll
        for (int j = 0; j < 6; ++j) {
            const bf16x8 bh  = *(const bf16x8*)&Bh[(j * 16 + fr) * 32 + kk];
            const bf16x8 bl2 = *(const bf16x8*)&Bl[(j * 16 + fr) * 32 + kk];
            acc[j] = __builtin_amdgcn_mfma_f32_16x16x32_bf16(ah,  bh,  acc[j], 0, 0, 0);
            acc[j] = __builtin_amdgcn_mfma_f32_16x16x32_bf16(ah,  bl2, acc[j], 0, 0, 0);
            acc[j] = __builtin_amdgcn_mfma_f32_16x16x32_bf16(al2, bh,  acc[j], 0, 0, 0);
        }
        __syncthreads();
    }
    float* p = part + (size_t)ks * (NROW * 96);
#pragma unroll
    for (int j = 0; j < 6; ++j)
#pragma unroll
        for (int r = 0; r < 4; ++r)
            p[(size_t)(bm + w * 16 + fq * 4 + r) * 96 + j * 16 + fr] = acc[j][r];
}

// ---------------- GEMM2 reduce: dbc = sum(part), dr -> split bf16 ----------------
__global__ __launch_bounds__(256)
void gemm2_reduce(const float* __restrict__ part, float* __restrict__ dbc,
                  unsigned short* __restrict__ drh, unsigned short* __restrict__ drl)
{
    const int idx = blockIdx.x * 256 + threadIdx.x;
    float s = 0.f;
#pragma unroll
    for (int ks = 0; ks < KS; ++ks) s += part[(size_t)ks * (NROW * 96) + idx];
    dbc[idx] = s;
    const int col = idx % 96;
    if (col < DR) {
        const int row = idx / 96;
        const unsigned short h = f2bf(s);
        drh[(size_t)row * DR + col] = h;
        drl[(size_t)row * DR + col] = f2bf(s - bf2f(h));
    }
}

// ---------------- GEMM3: delta = softplus(dr @ Wdt^T + bdt), split precision -------
__global__ __launch_bounds__(256)
void gemm3_delta(const unsigned short* __restrict__ Agh, const unsigned short* __restrict__ Agl,
                 const unsigned short* __restrict__ Bgh, const unsigned short* __restrict__ Bgl,
                 const float* __restrict__ bdt, float* __restrict__ delta)
{
    __shared__ unsigned short Ah[128 * 32], Al[128 * 32];
    __shared__ unsigned short Bh[128 * 32], Bl[128 * 32];
    const int tid = threadIdx.x;
    const int w = tid >> 6, l = tid & 63;
    const int bm = blockIdx.y * 128;
    const int bn = blockIdx.x * 128;
    const int wm = (w >> 1) * 64, wn = (w & 1) * 64;
    const int srow = w * 16 + (l >> 2);
    const int skel = (l & 3) * 8;
    const int kk = (l >> 4) * 8, fr = l & 15, fq = l >> 4;

    f32x4 acc[4][4] = {};
    for (int k0 = 0; k0 < DR; k0 += 32) {
        gload_lds16(Agh + (size_t)(bm + srow) * DR + k0 + skel,      &Ah[(w * 16) * 32]);
        gload_lds16(Agh + (size_t)(bm + 64 + srow) * DR + k0 + skel, &Ah[(64 + w * 16) * 32]);
        gload_lds16(Agl + (size_t)(bm + srow) * DR + k0 + skel,      &Al[(w * 16) * 32]);
        gload_lds16(Agl + (size_t)(bm + 64 + srow) * DR + k0 + skel, &Al[(64 + w * 16) * 32]);
        gload_lds16(Bgh + (size_t)(bn + srow) * DR + k0 + skel,      &Bh[(w * 16) * 32]);
        gload_lds16(Bgh + (size_t)(bn + 64 + srow) * DR + k0 + skel, &Bh[(64 + w * 16) * 32]);
        gload_lds16(Bgl + (size_t)(bn + srow) * DR + k0 + skel,      &Bl[(w * 16) * 32]);
        gload_lds16(Bgl + (size_t)(bn + 64 + srow) * DR + k0 + skel, &Bl[(64 + w * 16) * 32]);
        __syncthreads();
        bf16x8 ah[4], al2[4], bh[4], bl2[4];
#pragma unroll
        for (int i = 0; i < 4; ++i) {
            ah[i]  = *(const bf16x8*)&Ah[(wm + i * 16 + fr) * 32 + kk];
            al2[i] = *(const bf16x8*)&Al[(wm + i * 16 + fr) * 32 + kk];
        }
#pragma unroll
        for (int j = 0; j < 4; ++j) {
            bh[j]  = *(const bf16x8*)&Bh[(wn + j * 16 + fr) * 32 + kk];
            bl2[j] = *(const bf16x8*)&Bl[(wn + j * 16 + fr) * 32 + kk];
        }
#pragma unroll
        for (int i = 0; i < 4; ++i)
#pragma unroll
            for (int j = 0; j < 4; ++j) {
                acc[i][j] = __builtin_amdgcn_mfma_f32_16x16x32_bf16(ah[i],  bh[j],  acc[i][j], 0, 0, 0);
                acc[i][j] = __builtin_amdgcn_mfma_f32_16x16x32_bf16(ah[i],  bl2[j], acc[i][j], 0, 0, 0);
                acc[i][j] = __builtin_amdgcn_mfma_f32_16x16x32_bf16(al2[i], bh[j],  acc[i][j], 0, 0, 0);
            }
        __syncthreads();
    }
#pragma unroll
    for (int i = 0; i < 4; ++i)
#pragma unroll
        for (int j = 0; j < 4; ++j)
#pragma unroll
            for (int r = 0; r < 4; ++r) {
                const int row = bm + wm + i * 16 + fq * 4 + r;
                const int col = bn + wn + j * 16 + fr;
                delta[(size_t)row * DI + col] = softplus_f(acc[i][j][r] + bdt[col]);
            }
}

// ---------------- causal depthwise conv (K=4) + SiLU -> u split bf16 ----------------
__global__ __launch_bounds__(256)
void conv_silu_k(const float* __restrict__ xz, const float* __restrict__ cw,
                 const float* __restrict__ cb,
                 unsigned short* __restrict__ uh, unsigned short* __restrict__ ul)
{
    const size_t idx = (size_t)blockIdx.x * 256 + threadIdx.x;
    const int c = (int)(idx & (DI - 1));
    const size_t bl = idx >> 11;
    const int l = (int)(bl & (L_ - 1));
    const float4 w = *(const float4*)(cw + (size_t)c * 4);
    const float wk[4] = {w.x, w.y, w.z, w.w};
    float s = cb[c];
#pragma unroll
    for (int k = 0; k < 4; ++k) {
        const int t = l - 3 + k;
        if (t >= 0) s += xz[(bl - 3 + k) * (size_t)(2*DI) + c] * wk[k];
    }
    const float v = silu_f(s);
    const unsigned short h = f2bf(v);
    uh[idx] = h;
    ul[idx] = f2bf(v - bf2f(h));
}

// ---------------- selective scan: phase 1 ----------------
__global__ __launch_bounds__(256)
void scan_phase1(const float* __restrict__ delta,
                 const unsigned short* __restrict__ uh, const unsigned short* __restrict__ ul,
                 const float* __restrict__ dbc, const float* __restrict__ A_log,
                 float* __restrict__ Aprod, float* __restrict__ hfin)
{
    __shared__ float Bs[CH][N_];
    const int tid = threadIdx.x;
    const int d  = blockIdx.x * 256 + tid;
    const int ck = blockIdx.y;
    const int b  = blockIdx.z;
    const int l0 = ck * CH;
    for (int e = tid; e < CH * N_; e += 256) {
        const int lo = e >> 4, n = e & 15;
        Bs[lo][n] = dbc[((size_t)(b*L_ + l0 + lo)) * 96 + 64 + n];
    }
    __syncthreads();
    float An[N_], h[N_], P[N_];
#pragma unroll
    for (int n = 0; n < N_; ++n) {
        An[n] = -__expf(A_log[(size_t)d * N_ + n]);
        h[n] = 0.f; P[n] = 1.f;
    }
    size_t base = ((size_t)(b*L_ + l0)) * DI + d;
    for (int lo = 0; lo < CH; ++lo) {
        const float dl = delta[base];
        const float uu = bf2f(uh[base]) + bf2f(ul[base]);
        base += DI;
        const float du = dl * uu;
#pragma unroll
        for (int n = 0; n < N_; ++n) {
            const float da = __expf(dl * An[n]);
            h[n] = fmaf(da, h[n], du * Bs[lo][n]);
            P[n] *= da;
        }
    }
    const size_t o = (((size_t)(b*NCH + ck) * DI) + d) * N_;
#pragma unroll
    for (int n = 0; n < N_; n += 4) {
        *(float4*)(Aprod + o + n) = make_float4(P[n], P[n+1], P[n+2], P[n+3]);
        *(float4*)(hfin  + o + n) = make_float4(h[n], h[n+1], h[n+2], h[n+3]);
    }
}

// ---------------- selective scan: phase 2 (hinit MAY ALIAS Aprod: load-before-store) ----
__global__ __launch_bounds__(256)
void scan_phase2(const float* Aprod, const float* __restrict__ hfin, float* hinit)
{
    const size_t idx = (size_t)blockIdx.x * 256 + threadIdx.x;
    const int b = (idx >= (size_t)DI * N_) ? 1 : 0;
    const size_t dn = idx - (size_t)b * DI * N_;
    float h = 0.f;
    for (int c = 0; c < NCH; ++c) {
        const size_t o = ((size_t)(b*NCH + c) * DI) * N_ + dn;
        const float a = Aprod[o];
        const float f = hfin[o];
        hinit[o] = h;
        h = fmaf(a, h, f);
    }
}

// ---------------- selective scan: phase 3 (replay + y + gate -> bf16 g) ----------------
__global__ __launch_bounds__(256)
void scan_phase3(const float* __restrict__ delta,
                 const unsigned short* __restrict__ uh, const unsigned short* __restrict__ ul,
                 const float* __restrict__ dbc, const float* __restrict__ A_log,
                 const float* __restrict__ hinit, const float* __restrict__ Dp,
                 const float* __restrict__ xz, unsigned short* __restrict__ gb)
{
    __shared__ float Bs[CH][N_];
    __shared__ float Cs[CH][N_];
    const int tid = threadIdx.x;
    const int d  = blockIdx.x * 256 + tid;
    const int ck = blockIdx.y;
    const int b  = blockIdx.z;
    const int l0 = ck * CH;
    for (int e = tid; e < CH * N_; e += 256) {
        const int lo = e >> 4, n = e & 15;
        const size_t r = ((size_t)(b*L_ + l0 + lo)) * 96;
        Bs[lo][n] = dbc[r + 64 + n];
        Cs[lo][n] = dbc[r + 80 + n];
    }
    __syncthreads();
    float An[N_], h[N_];
    const size_t ho = (((size_t)(b*NCH + ck) * DI) + d) * N_;
#pragma unroll
    for (int n = 0; n < N_; n += 4) {
        const float4 hv = *(const float4*)(hinit + ho + n);
        h[n] = hv.x; h[n+1] = hv.y; h[n+2] = hv.z; h[n+3] = hv.w;
    }
#pragma unroll
    for (int n = 0; n < N_; ++n)
        An[n] = -__expf(A_log[(size_t)d * N_ + n]);
    const float dp = Dp[d];
    size_t base  = ((size_t)(b*L_ + l0)) * DI + d;
    size_t zbase = ((size_t)(b*L_ + l0)) * (2*DI) + DI + d;
    size_t gidx  = ((size_t)(b*L_ + l0)) * DI + d;
    for (int lo = 0; lo < CH; ++lo) {
        const float dl = delta[base];
        const float uu = bf2f(uh[base]) + bf2f(ul[base]);
        base += DI;
        const float du = dl * uu;
        float y = 0.f;
#pragma unroll
        for (int n = 0; n < N_; ++n) {
            const float da = __expf(dl * An[n]);
            h[n] = fmaf(da, h[n], du * Bs[lo][n]);
            y = fmaf(h[n], Cs[lo][n], y);
        }
        y = fmaf(dp, uu, y);
        const float zz = xz[zbase]; zbase += 2*DI;
        gb[gidx] = f2bf(y * silu_f(zz)); gidx += DI;
    }
}

extern "C" void kernel_launch(void* const* d_in, const int* in_sizes, int n_in,
                              void* d_out, int out_size, void* d_ws, size_t ws_size,
                              hipStream_t stream)
{
    const float* x     = (const float*)d_in[0];
    const float* Win   = (const float*)d_in[1];
    const float* cw    = (const float*)d_in[2];
    const float* cb    = (const float*)d_in[3];
    const float* Wx    = (const float*)d_in[4];
    const float* Wdt   = (const float*)d_in[5];
    const float* bdt   = (const float*)d_in[6];
    const float* A_log = (const float*)d_in[7];
    const float* Dp    = (const float*)d_in[8];
    const float* Wout  = (const float*)d_in[9];
    float* out = (float*)d_out;

    float* ws    = (float*)d_ws;
    float* xz    = ws;                                    // NROW*2*DI f32
    float* delta = xz    + (size_t)NROW * 2 * DI;         // NROW*DI f32
    float* dbc   = delta + (size_t)NROW * DI;             // NROW*96 f32
    float* Aprod = dbc   + (size_t)NROW * 96;             // B_*NCH*DI*N_ f32
    float* hfin  = Aprod + (size_t)B_ * NCH * DI * N_;    // B_*NCH*DI*N_ f32
    float* hinit = Aprod;                                 // ALIASES Aprod (phase2 load-before-store)
    unsigned short* uh  = (unsigned short*)(hfin + (size_t)B_ * NCH * DI * N_);  // NROW*DI
    unsigned short* ul  = uh  + (size_t)NROW * DI;
    unsigned short* xb  = ul  + (size_t)NROW * DI;        // NROW*DM (dead after GEMM1)
    unsigned short* wb  = xb  + (size_t)NROW * DM;        // 2DI*DM  (dead after GEMM1)
    unsigned short* wob = wb  + (size_t)(2*DI) * DM;      // DM*DI
    unsigned short* gb  = wob + (size_t)DM * DI;          // NROW*DI
    unsigned short* wxh = gb  + (size_t)NROW * DI;        // 96*DI
    unsigned short* wxl = wxh + (size_t)96 * DI;
    unsigned short* wdh = wxl + (size_t)96 * DI;          // DI*DR
    unsigned short* wdl = wdh + (size_t)DI * DR;
    float* part = (float*)xb;                             // KS*NROW*96 f32 (dead xb/wb region)
    unsigned short* drh = (unsigned short*)(part + (size_t)KS * NROW * 96);  // NROW*DR
    unsigned short* drl = drh + (size_t)NROW * DR;

    const dim3 blk(256);

    // 0) conversions
    f32_to_bf16_k<<<dim3((NROW*DM)/8/256), blk, 0, stream>>>(x,    xb,  (NROW*DM)/8);
    f32_to_bf16_k<<<dim3((2*DI*DM)/8/256), blk, 0, stream>>>(Win,  wb,  (2*DI*DM)/8);
    f32_to_bf16_k<<<dim3((DM*DI)/8/256),   blk, 0, stream>>>(Wout, wob, (DM*DI)/8);
    f32_to_bf16_split_k<<<dim3((96*DI+255)/256),  blk, 0, stream>>>(Wx,  wxh, wxl, 96*DI);
    f32_to_bf16_split_k<<<dim3((DI*DR+255)/256),  blk, 0, stream>>>(Wdt, wdh, wdl, DI*DR);
    // 1) xz = x @ Win^T   (4096 x 4096 x 1024, 256^2 pipelined MFMA)
    gemm_bf16_256<<<dim3((2*DI)/256, NROW/256), dim3(512), 0, stream>>>(xb, wb, xz, 2*DI, DM);
    // 2) u = silu(conv1d(xin)) -> split bf16
    conv_silu_k<<<dim3((NROW * DI) / 256), blk, 0, stream>>>(xz, cw, cb, uh, ul);
    // 3) dbc = u @ Wx^T   (split-K bf16 MFMA + reduce)
    gemm2_splitk<<<dim3(KS, NROW/64), blk, 0, stream>>>(uh, ul, wxh, wxl, part);
    gemm2_reduce<<<dim3((NROW*96)/256), blk, 0, stream>>>(part, dbc, drh, drl);
    // 4) delta = softplus(dr @ Wdt^T + bdt)   (split bf16 MFMA)
    gemm3_delta<<<dim3(DI/128, NROW/128), blk, 0, stream>>>(drh, drl, wdh, wdl, bdt, delta);
    // 5-7) chunked selective scan
    scan_phase1<<<dim3(DI/256, NCH, B_), blk, 0, stream>>>(delta, uh, ul, dbc, A_log, Aprod, hfin);
    scan_phase2<<<dim3((B_*DI*N_)/256), blk, 0, stream>>>(Aprod, hfin, hinit);
    scan_phase3<<<dim3(DI/256, NCH, B_), blk, 0, stream>>>(delta, uh, ul, dbc, A_log, hinit, Dp, xz, gb);
    // 8) out = g @ Wout^T  (4096 x 1024 x 2048, 256^2 pipelined MFMA)
    gemm_bf16_256<<<dim3(DM/256, NROW/256), dim3(512), 0, stream>>>(gb, wob, out, DM, DI);
}

// Round 6
// 262.209 us; speedup vs baseline: 3.6781x; 1.0065x over previous
//
#include <hip/hip_runtime.h>
#include <math.h>

#define B_  2
#define L_  2048
#define DM  1024
#define DI  2048
#define DR  64
#define N_  16
#define K_  4
#define NROW (B_*L_)      // 4096
#define CH  64
#define NCH (L_/CH)       // 32
#define KS  8             // split-K factor for GEMM2

typedef __attribute__((ext_vector_type(8))) __bf16 bf16x8;
typedef __attribute__((ext_vector_type(4))) float f32x4;

__device__ __forceinline__ float silu_f(float x) { return x / (1.0f + __expf(-x)); }

// branch-free softplus from native v_exp_f32 / v_log_f32 only (no log1pf libcall)
__device__ __forceinline__ float softplus_f(float v) {
    return fmaxf(v, 0.0f) + __logf(1.0f + __expf(-fabsf(v)));
}

__device__ __forceinline__ unsigned short f2bf(float f) {
    unsigned u = __float_as_uint(f);
    unsigned r = (u + 0x7FFF + ((u >> 16) & 1)) >> 16;  // RNE
    return (unsigned short)r;
}
__device__ __forceinline__ float bf2f(unsigned short h) {
    return __uint_as_float(((unsigned)h) << 16);
}

__device__ __forceinline__ void gload_lds16(const void* g, void* l) {
    __builtin_amdgcn_global_load_lds(
        (const __attribute__((address_space(1))) void*)g,
        (__attribute__((address_space(3))) void*)l,
        16, 0, 0);
}

// ---------------- fp32 -> bf16 (8 elems/thread) ----------------
__global__ __launch_bounds__(256)
void f32_to_bf16_k(const float* __restrict__ in, unsigned short* __restrict__ out, int n8)
{
    const int i = blockIdx.x * 256 + threadIdx.x;
    if (i >= n8) return;
    const float4 a = *((const float4*)in + (size_t)i * 2);
    const float4 b = *((const float4*)in + (size_t)i * 2 + 1);
    union { unsigned short s[8]; uint4 v; } o;
    o.s[0] = f2bf(a.x); o.s[1] = f2bf(a.y); o.s[2] = f2bf(a.z); o.s[3] = f2bf(a.w);
    o.s[4] = f2bf(b.x); o.s[5] = f2bf(b.y); o.s[6] = f2bf(b.z); o.s[7] = f2bf(b.w);
    *(uint4*)(out + (size_t)i * 8) = o.v;
}

// ---------------- fp32 -> split bf16 (hi + lo) ----------------
__global__ __launch_bounds__(256)
void f32_to_bf16_split_k(const float* __restrict__ in,
                         unsigned short* __restrict__ hi,
                         unsigned short* __restrict__ lo, int n)
{
    const int i = blockIdx.x * 256 + threadIdx.x;
    if (i >= n) return;
    const float v = in[i];
    const unsigned short h = f2bf(v);
    hi[i] = h;
    lo[i] = f2bf(v - bf2f(h));
}

// ============ 256x256 bf16 MFMA NT GEMM, quad-buffered LDS, counted vmcnt ============
// C[MxN] = A[MxK] * B[NxK]^T.  M%256==0, N%256==0, K%32==0, K>=128.
// 512 threads = 8 waves (2M x 4N); per-wave output 128x64 (8x4 16x16 frags).
// LDS 128 KiB: A/B each 4 buffers of 256x32 bf16. Prefetch depth 3 tiles;
// ledger: vmcnt(8) mid-loop [never 0], vmcnt(4)/(0) for last two tiles.
// R6: per-tile TWO interleaved phases (reads+stage | bar | lgkm | 16 MFMA |
// readB under MFMA drain | bar | lgkm | 16 MFMA) -> wave role-split (T3-lite+T5).
// Swizzle: slot' = slot ^ ((row>>1)&3) via inverse-permuted GLOBAL source
// (linear gload_lds dest) + same XOR on read (rule 21).
__global__ __launch_bounds__(512, 2)
void gemm_bf16_256(const unsigned short* __restrict__ A,
                   const unsigned short* __restrict__ B,
                   float* __restrict__ C, int ldc, int K)
{
    __shared__ unsigned short lds[65536];   // 128 KiB
    const int tid = threadIdx.x;
    const int w = tid >> 6;          // wave 0..7
    const int l = tid & 63;
    const int wM = w >> 2;           // 0..1
    const int wN = w & 3;            // 0..3

    // XCD-aware block swizzle (grid sizes here are multiples of 8)
    const int nbx = gridDim.x;
    const int nwg = nbx * gridDim.y;
    int flat = blockIdx.y * nbx + blockIdx.x;
    flat = (flat & 7) * (nwg >> 3) + (flat >> 3);
    const int bn = (flat % nbx) * 256;
    const int bm = (flat / nbx) * 256;

    // ---- staging addresses (rule 21: linear LDS dest, inverse-swizzled source) ----
    const int ksrc = (((l & 3) ^ ((l >> 3) & 3)) * 8);      // element offset in 32-k chunk
    const int srow = w * 16 + (l >> 2);
    const unsigned short* a0 = A + (size_t)(bm + srow) * K + ksrc;
    const unsigned short* a1 = A + (size_t)(bm + 128 + srow) * K + ksrc;
    const unsigned short* b0 = B + (size_t)(bn + srow) * K + ksrc;
    const unsigned short* b1 = B + (size_t)(bn + 128 + srow) * K + ksrc;
    char* ldsc = (char*)lds;

    auto stage = [&](int p, int kof) {   // p = buffer index, kof = element k-offset
        char* d = ldsc + p * 16384 + w * 1024;
        gload_lds16(a0 + kof, d);
        gload_lds16(a1 + kof, d + 8192);
        gload_lds16(b0 + kof, d + 65536);
        gload_lds16(b1 + kof, d + 65536 + 8192);
    };

    // ---- fragment read offsets (elements), swizzled ----
    const int fr = l & 15, fq = l >> 4;
    const int slotr = fq ^ ((fr >> 1) & 3);
    int aoff[8], boff[4];
#pragma unroll
    for (int i = 0; i < 8; ++i) aoff[i] = (wM * 128 + i * 16 + fr) * 32 + slotr * 8;
#pragma unroll
    for (int j = 0; j < 4; ++j) boff[j] = (wN * 64 + j * 16 + fr) * 32 + slotr * 8;

    f32x4 acc[8][4] = {};
    const int NT = K >> 5;

    // prologue: tiles 0,1,2 in flight (12 loads/thread)
    stage(0, 0);
    stage(1, 32);
    stage(2, 64);

    for (int t = 0; t < NT; ++t) {
        const int rem = NT - 1 - t;
        if (rem >= 2)      asm volatile("s_waitcnt vmcnt(8)" ::: "memory");
        else if (rem == 1) asm volatile("s_waitcnt vmcnt(4)" ::: "memory");
        else               asm volatile("s_waitcnt vmcnt(0)" ::: "memory");
        __builtin_amdgcn_s_barrier();                 // B1: tile t visible to all
        __builtin_amdgcn_sched_barrier(0);

        const unsigned short* Ab = lds + (t & 3) * 8192;
        const unsigned short* Bb = lds + 32768 + (t & 3) * 8192;

        // ---- phase 0: frag reads (A-half0 + all B) + prefetch stage ----
        bf16x8 af0[4], af1[4], bf[4];
#pragma unroll
        for (int i = 0; i < 4; ++i) af0[i] = *(const bf16x8*)(Ab + aoff[i]);
#pragma unroll
        for (int j = 0; j < 4; ++j) bf[j] = *(const bf16x8*)(Bb + boff[j]);
        if (t + 3 < NT) stage((t + 3) & 3, (t + 3) * 32);

        __builtin_amdgcn_s_barrier();                 // B2: phase lock
        asm volatile("s_waitcnt lgkmcnt(0)" ::: "memory");
        __builtin_amdgcn_sched_barrier(0);
        __builtin_amdgcn_s_setprio(1);
#pragma unroll
        for (int i = 0; i < 4; ++i)
#pragma unroll
            for (int j = 0; j < 4; ++j)
                acc[i][j] = __builtin_amdgcn_mfma_f32_16x16x32_bf16(af0[i], bf[j], acc[i][j], 0, 0, 0);
        __builtin_amdgcn_s_setprio(0);

        // ---- phase 1: A-half1 reads issue under cluster-0 MFMA drain ----
#pragma unroll
        for (int i = 0; i < 4; ++i) af1[i] = *(const bf16x8*)(Ab + aoff[4 + i]);
        __builtin_amdgcn_sched_barrier(0);            // pin reads before B3
        __builtin_amdgcn_s_barrier();                 // B3
        asm volatile("s_waitcnt lgkmcnt(0)" ::: "memory");
        __builtin_amdgcn_sched_barrier(0);
        __builtin_amdgcn_s_setprio(1);
#pragma unroll
        for (int i = 0; i < 4; ++i)
#pragma unroll
            for (int j = 0; j < 4; ++j)
                acc[4 + i][j] = __builtin_amdgcn_mfma_f32_16x16x32_bf16(af1[i], bf[j], acc[4 + i][j], 0, 0, 0);
        __builtin_amdgcn_s_setprio(0);
    }

#pragma unroll
    for (int i = 0; i < 8; ++i)
#pragma unroll
        for (int j = 0; j < 4; ++j)
#pragma unroll
            for (int r = 0; r < 4; ++r) {
                const int row = bm + wM * 128 + i * 16 + fq * 4 + r;
                const int col = bn + wN * 64 + j * 16 + fr;
                C[(size_t)row * ldc + col] = acc[i][j][r];
            }
}

// ---------------- GEMM2 split-K: part[ks] += u[64rows x 256k] @ Wx^T (96 cols) --------
__global__ __launch_bounds__(256)
void gemm2_splitk(const unsigned short* __restrict__ uh, const unsigned short* __restrict__ ul,
                  const unsigned short* __restrict__ wxh, const unsigned short* __restrict__ wxl,
                  float* __restrict__ part)
{
    __shared__ unsigned short Ah[64 * 32], Al[64 * 32];
    __shared__ unsigned short Bh[96 * 32], Bl[96 * 32];
    const int tid = threadIdx.x;
    const int w = tid >> 6, l = tid & 63;
    const int ks = blockIdx.x;
    const int bm = blockIdx.y * 64;
    const int kbase = ks * (DI / KS);
    const int srow = l >> 2;
    const int skel = (l & 3) * 8;
    const int kk = (l >> 4) * 8, fr = l & 15, fq = l >> 4;

    f32x4 acc[6] = {};
    for (int k0 = 0; k0 < DI / KS; k0 += 32) {
        const int kg = kbase + k0;
        gload_lds16(uh  + (size_t)(bm + w * 16 + srow) * DI + kg + skel, &Ah[(w * 16) * 32]);
        gload_lds16(ul  + (size_t)(bm + w * 16 + srow) * DI + kg + skel, &Al[(w * 16) * 32]);
        gload_lds16(wxh + (size_t)(w * 16 + srow) * DI + kg + skel, &Bh[(w * 16) * 32]);
        gload_lds16(wxl + (size_t)(w * 16 + srow) * DI + kg + skel, &Bl[(w * 16) * 32]);
        if (w < 2) {
            gload_lds16(wxh + (size_t)(64 + w * 16 + srow) * DI + kg + skel, &Bh[(64 + w * 16) * 32]);
            gload_lds16(wxl + (size_t)(64 + w * 16 + srow) * DI + kg + skel, &Bl[(64 + w * 16) * 32]);
        }
        __syncthreads();
        const bf16x8 ah  = *(const bf16x8*)&Ah[(w * 16 + fr) * 32 + kk];
        const bf16x8 al2 = *(const bf16x8*)&Al[(w * 16 + fr) * 32 + kk];
#pragma unroll
        for (int j = 0; j < 6; ++j) {
            const bf16x8 bh  = *(const bf16x8*)&Bh[(j * 16 + fr) * 32 + kk];
            const bf16x8 bl2 = *(const bf16x8*)&Bl[(j * 16 + fr) * 32 + kk];
            acc[j] = __builtin_amdgcn_mfma_f32_16x16x32_bf16(ah,  bh,  acc[j], 0, 0, 0);
            acc[j] = __builtin_amdgcn_mfma_f32_16x16x32_bf16(ah,  bl2, acc[j], 0, 0, 0);
            acc[j] = __builtin_amdgcn_mfma_f32_16x16x32_bf16(al2, bh,  acc[j], 0, 0, 0);
        }
        __syncthreads();
    }
    float* p = part + (size_t)ks * (NROW * 96);
#pragma unroll
    for (int j = 0; j < 6; ++j)
#pragma unroll
        for (int r = 0; r < 4; ++r)
            p[(size_t)(bm + w * 16 + fq * 4 + r) * 96 + j * 16 + fr] = acc[j][r];
}

// ---------------- GEMM2 reduce: dbc = sum(part), dr -> split bf16 ----------------
__global__ __launch_bounds__(256)
void gemm2_reduce(const float* __restrict__ part, float* __restrict__ dbc,
                  unsigned short* __restrict__ drh, unsigned short* __restrict__ drl)
{
    const int idx = blockIdx.x * 256 + threadIdx.x;
    float s = 0.f;
#pragma unroll
    for (int ks = 0; ks < KS; ++ks) s += part[(size_t)ks * (NROW * 96) + idx];
    dbc[idx] = s;
    const int col = idx % 96;
    if (col < DR) {
        const int row = idx / 96;
        const unsigned short h = f2bf(s);
        drh[(size_t)row * DR + col] = h;
        drl[(size_t)row * DR + col] = f2bf(s - bf2f(h));
    }
}

// ---------------- GEMM3: delta = softplus(dr @ Wdt^T + bdt), split precision -------
__global__ __launch_bounds__(256)
void gemm3_delta(const unsigned short* __restrict__ Agh, const unsigned short* __restrict__ Agl,
                 const unsigned short* __restrict__ Bgh, const unsigned short* __restrict__ Bgl,
                 const float* __restrict__ bdt, float* __restrict__ delta)
{
    __shared__ unsigned short Ah[128 * 32], Al[128 * 32];
    __shared__ unsigned short Bh[128 * 32], Bl[128 * 32];
    const int tid = threadIdx.x;
    const int w = tid >> 6, l = tid & 63;
    const int bm = blockIdx.y * 128;
    const int bn = blockIdx.x * 128;
    const int wm = (w >> 1) * 64, wn = (w & 1) * 64;
    const int srow = w * 16 + (l >> 2);
    const int skel = (l & 3) * 8;
    const int kk = (l >> 4) * 8, fr = l & 15, fq = l >> 4;

    f32x4 acc[4][4] = {};
    for (int k0 = 0; k0 < DR; k0 += 32) {
        gload_lds16(Agh + (size_t)(bm + srow) * DR + k0 + skel,      &Ah[(w * 16) * 32]);
        gload_lds16(Agh + (size_t)(bm + 64 + srow) * DR + k0 + skel, &Ah[(64 + w * 16) * 32]);
        gload_lds16(Agl + (size_t)(bm + srow) * DR + k0 + skel,      &Al[(w * 16) * 32]);
        gload_lds16(Agl + (size_t)(bm + 64 + srow) * DR + k0 + skel, &Al[(64 + w * 16) * 32]);
        gload_lds16(Bgh + (size_t)(bn + srow) * DR + k0 + skel,      &Bh[(w * 16) * 32]);
        gload_lds16(Bgh + (size_t)(bn + 64 + srow) * DR + k0 + skel, &Bh[(64 + w * 16) * 32]);
        gload_lds16(Bgl + (size_t)(bn + srow) * DR + k0 + skel,      &Bl[(w * 16) * 32]);
        gload_lds16(Bgl + (size_t)(bn + 64 + srow) * DR + k0 + skel, &Bl[(64 + w * 16) * 32]);
        __syncthreads();
        bf16x8 ah[4], al2[4], bh[4], bl2[4];
#pragma unroll
        for (int i = 0; i < 4; ++i) {
            ah[i]  = *(const bf16x8*)&Ah[(wm + i * 16 + fr) * 32 + kk];
            al2[i] = *(const bf16x8*)&Al[(wm + i * 16 + fr) * 32 + kk];
        }
#pragma unroll
        for (int j = 0; j < 4; ++j) {
            bh[j]  = *(const bf16x8*)&Bh[(wn + j * 16 + fr) * 32 + kk];
            bl2[j] = *(const bf16x8*)&Bl[(wn + j * 16 + fr) * 32 + kk];
        }
#pragma unroll
        for (int i = 0; i < 4; ++i)
#pragma unroll
            for (int j = 0; j < 4; ++j) {
                acc[i][j] = __builtin_amdgcn_mfma_f32_16x16x32_bf16(ah[i],  bh[j],  acc[i][j], 0, 0, 0);
                acc[i][j] = __builtin_amdgcn_mfma_f32_16x16x32_bf16(ah[i],  bl2[j], acc[i][j], 0, 0, 0);
                acc[i][j] = __builtin_amdgcn_mfma_f32_16x16x32_bf16(al2[i], bh[j],  acc[i][j], 0, 0, 0);
            }
        __syncthreads();
    }
#pragma unroll
    for (int i = 0; i < 4; ++i)
#pragma unroll
        for (int j = 0; j < 4; ++j)
#pragma unroll
            for (int r = 0; r < 4; ++r) {
                const int row = bm + wm + i * 16 + fq * 4 + r;
                const int col = bn + wn + j * 16 + fr;
                delta[(size_t)row * DI + col] = softplus_f(acc[i][j][r] + bdt[col]);
            }
}

// ---------------- causal depthwise conv (K=4) + SiLU -> u split bf16 ----------------
__global__ __launch_bounds__(256)
void conv_silu_k(const float* __restrict__ xz, const float* __restrict__ cw,
                 const float* __restrict__ cb,
                 unsigned short* __restrict__ uh, unsigned short* __restrict__ ul)
{
    const size_t idx = (size_t)blockIdx.x * 256 + threadIdx.x;
    const int c = (int)(idx & (DI - 1));
    const size_t bl = idx >> 11;
    const int l = (int)(bl & (L_ - 1));
    const float4 w = *(const float4*)(cw + (size_t)c * 4);
    const float wk[4] = {w.x, w.y, w.z, w.w};
    float s = cb[c];
#pragma unroll
    for (int k = 0; k < 4; ++k) {
        const int t = l - 3 + k;
        if (t >= 0) s += xz[(bl - 3 + k) * (size_t)(2*DI) + c] * wk[k];
    }
    const float v = silu_f(s);
    const unsigned short h = f2bf(v);
    uh[idx] = h;
    ul[idx] = f2bf(v - bf2f(h));
}

// ---------------- selective scan: phase 1 ----------------
__global__ __launch_bounds__(256)
void scan_phase1(const float* __restrict__ delta,
                 const unsigned short* __restrict__ uh, const unsigned short* __restrict__ ul,
                 const float* __restrict__ dbc, const float* __restrict__ A_log,
                 float* __restrict__ Aprod, float* __restrict__ hfin)
{
    __shared__ float Bs[CH][N_];
    const int tid = threadIdx.x;
    const int d  = blockIdx.x * 256 + tid;
    const int ck = blockIdx.y;
    const int b  = blockIdx.z;
    const int l0 = ck * CH;
    for (int e = tid; e < CH * N_; e += 256) {
        const int lo = e >> 4, n = e & 15;
        Bs[lo][n] = dbc[((size_t)(b*L_ + l0 + lo)) * 96 + 64 + n];
    }
    __syncthreads();
    float An[N_], h[N_], P[N_];
#pragma unroll
    for (int n = 0; n < N_; ++n) {
        An[n] = -__expf(A_log[(size_t)d * N_ + n]);
        h[n] = 0.f; P[n] = 1.f;
    }
    size_t base = ((size_t)(b*L_ + l0)) * DI + d;
    for (int lo = 0; lo < CH; ++lo) {
        const float dl = delta[base];
        const float uu = bf2f(uh[base]) + bf2f(ul[base]);
        base += DI;
        const float du = dl * uu;
#pragma unroll
        for (int n = 0; n < N_; ++n) {
            const float da = __expf(dl * An[n]);
            h[n] = fmaf(da, h[n], du * Bs[lo][n]);
            P[n] *= da;
        }
    }
    const size_t o = (((size_t)(b*NCH + ck) * DI) + d) * N_;
#pragma unroll
    for (int n = 0; n < N_; n += 4) {
        *(float4*)(Aprod + o + n) = make_float4(P[n], P[n+1], P[n+2], P[n+3]);
        *(float4*)(hfin  + o + n) = make_float4(h[n], h[n+1], h[n+2], h[n+3]);
    }
}

// ---------------- selective scan: phase 2 (hinit MAY ALIAS Aprod: load-before-store) ----
__global__ __launch_bounds__(256)
void scan_phase2(const float* Aprod, const float* __restrict__ hfin, float* hinit)
{
    const size_t idx = (size_t)blockIdx.x * 256 + threadIdx.x;
    const int b = (idx >= (size_t)DI * N_) ? 1 : 0;
    const size_t dn = idx - (size_t)b * DI * N_;
    float h = 0.f;
    for (int c = 0; c < NCH; ++c) {
        const size_t o = ((size_t)(b*NCH + c) * DI) * N_ + dn;
        const float a = Aprod[o];
        const float f = hfin[o];
        hinit[o] = h;
        h = fmaf(a, h, f);
    }
}

// ---------------- selective scan: phase 3 (replay + y + gate -> bf16 g) ----------------
__global__ __launch_bounds__(256)
void scan_phase3(const float* __restrict__ delta,
                 const unsigned short* __restrict__ uh, const unsigned short* __restrict__ ul,
                 const float* __restrict__ dbc, const float* __restrict__ A_log,
                 const float* __restrict__ hinit, const float* __restrict__ Dp,
                 const float* __restrict__ xz, unsigned short* __restrict__ gb)
{
    __shared__ float Bs[CH][N_];
    __shared__ float Cs[CH][N_];
    const int tid = threadIdx.x;
    const int d  = blockIdx.x * 256 + tid;
    const int ck = blockIdx.y;
    const int b  = blockIdx.z;
    const int l0 = ck * CH;
    for (int e = tid; e < CH * N_; e += 256) {
        const int lo = e >> 4, n = e & 15;
        const size_t r = ((size_t)(b*L_ + l0 + lo)) * 96;
        Bs[lo][n] = dbc[r + 64 + n];
        Cs[lo][n] = dbc[r + 80 + n];
    }
    __syncthreads();
    float An[N_], h[N_];
    const size_t ho = (((size_t)(b*NCH + ck) * DI) + d) * N_;
#pragma unroll
    for (int n = 0; n < N_; n += 4) {
        const float4 hv = *(const float4*)(hinit + ho + n);
        h[n] = hv.x; h[n+1] = hv.y; h[n+2] = hv.z; h[n+3] = hv.w;
    }
#pragma unroll
    for (int n = 0; n < N_; ++n)
        An[n] = -__expf(A_log[(size_t)d * N_ + n]);
    const float dp = Dp[d];
    size_t base  = ((size_t)(b*L_ + l0)) * DI + d;
    size_t zbase = ((size_t)(b*L_ + l0)) * (2*DI) + DI + d;
    size_t gidx  = ((size_t)(b*L_ + l0)) * DI + d;
    for (int lo = 0; lo < CH; ++lo) {
        const float dl = delta[base];
        const float uu = bf2f(uh[base]) + bf2f(ul[base]);
        base += DI;
        const float du = dl * uu;
        float y = 0.f;
#pragma unroll
        for (int n = 0; n < N_; ++n) {
            const float da = __expf(dl * An[n]);
            h[n] = fmaf(da, h[n], du * Bs[lo][n]);
            y = fmaf(h[n], Cs[lo][n], y);
        }
        y = fmaf(dp, uu, y);
        const float zz = xz[zbase]; zbase += 2*DI;
        gb[gidx] = f2bf(y * silu_f(zz)); gidx += DI;
    }
}

extern "C" void kernel_launch(void* const* d_in, const int* in_sizes, int n_in,
                              void* d_out, int out_size, void* d_ws, size_t ws_size,
                              hipStream_t stream)
{
    const float* x     = (const float*)d_in[0];
    const float* Win   = (const float*)d_in[1];
    const float* cw    = (const float*)d_in[2];
    const float* cb    = (const float*)d_in[3];
    const float* Wx    = (const float*)d_in[4];
    const float* Wdt   = (const float*)d_in[5];
    const float* bdt   = (const float*)d_in[6];
    const float* A_log = (const float*)d_in[7];
    const float* Dp    = (const float*)d_in[8];
    const float* Wout  = (const float*)d_in[9];
    float* out = (float*)d_out;

    float* ws    = (float*)d_ws;
    float* xz    = ws;                                    // NROW*2*DI f32
    float* delta = xz    + (size_t)NROW * 2 * DI;         // NROW*DI f32
    float* dbc   = delta + (size_t)NROW * DI;             // NROW*96 f32
    float* Aprod = dbc   + (size_t)NROW * 96;             // B_*NCH*DI*N_ f32
    float* hfin  = Aprod + (size_t)B_ * NCH * DI * N_;    // B_*NCH*DI*N_ f32
    float* hinit = Aprod;                                 // ALIASES Aprod (phase2 load-before-store)
    unsigned short* uh  = (unsigned short*)(hfin + (size_t)B_ * NCH * DI * N_);  // NROW*DI
    unsigned short* ul  = uh  + (size_t)NROW * DI;
    unsigned short* xb  = ul  + (size_t)NROW * DI;        // NROW*DM (dead after GEMM1)
    unsigned short* wb  = xb  + (size_t)NROW * DM;        // 2DI*DM  (dead after GEMM1)
    unsigned short* wob = wb  + (size_t)(2*DI) * DM;      // DM*DI
    unsigned short* gb  = wob + (size_t)DM * DI;          // NROW*DI
    unsigned short* wxh = gb  + (size_t)NROW * DI;        // 96*DI
    unsigned short* wxl = wxh + (size_t)96 * DI;
    unsigned short* wdh = wxl + (size_t)96 * DI;          // DI*DR
    unsigned short* wdl = wdh + (size_t)DI * DR;
    float* part = (float*)xb;                             // KS*NROW*96 f32 (dead xb/wb region)
    unsigned short* drh = (unsigned short*)(part + (size_t)KS * NROW * 96);  // NROW*DR
    unsigned short* drl = drh + (size_t)NROW * DR;

    const dim3 blk(256);

    // 0) conversions
    f32_to_bf16_k<<<dim3((NROW*DM)/8/256), blk, 0, stream>>>(x,    xb,  (NROW*DM)/8);
    f32_to_bf16_k<<<dim3((2*DI*DM)/8/256), blk, 0, stream>>>(Win,  wb,  (2*DI*DM)/8);
    f32_to_bf16_k<<<dim3((DM*DI)/8/256),   blk, 0, stream>>>(Wout, wob, (DM*DI)/8);
    f32_to_bf16_split_k<<<dim3((96*DI+255)/256),  blk, 0, stream>>>(Wx,  wxh, wxl, 96*DI);
    f32_to_bf16_split_k<<<dim3((DI*DR+255)/256),  blk, 0, stream>>>(Wdt, wdh, wdl, DI*DR);
    // 1) xz = x @ Win^T   (4096 x 4096 x 1024, 256^2 pipelined MFMA)
    gemm_bf16_256<<<dim3((2*DI)/256, NROW/256), dim3(512), 0, stream>>>(xb, wb, xz, 2*DI, DM);
    // 2) u = silu(conv1d(xin)) -> split bf16
    conv_silu_k<<<dim3((NROW * DI) / 256), blk, 0, stream>>>(xz, cw, cb, uh, ul);
    // 3) dbc = u @ Wx^T   (split-K bf16 MFMA + reduce)
    gemm2_splitk<<<dim3(KS, NROW/64), blk, 0, stream>>>(uh, ul, wxh, wxl, part);
    gemm2_reduce<<<dim3((NROW*96)/256), blk, 0, stream>>>(part, dbc, drh, drl);
    // 4) delta = softplus(dr @ Wdt^T + bdt)   (split bf16 MFMA)
    gemm3_delta<<<dim3(DI/128, NROW/128), blk, 0, stream>>>(drh, drl, wdh, wdl, bdt, delta);
    // 5-7) chunked selective scan
    scan_phase1<<<dim3(DI/256, NCH, B_), blk, 0, stream>>>(delta, uh, ul, dbc, A_log, Aprod, hfin);
    scan_phase2<<<dim3((B_*DI*N_)/256), blk, 0, stream>>>(Aprod, hfin, hinit);
    scan_phase3<<<dim3(DI/256, NCH, B_), blk, 0, stream>>>(delta, uh, ul, dbc, A_log, hinit, Dp, xz, gb);
    // 8) out = g @ Wout^T  (4096 x 1024 x 2048, 256^2 pipelined MFMA)
    gemm_bf16_256<<<dim3(DM/256, NROW/256), dim3(512), 0, stream>>>(gb, wob, out, DM, DI);
}

// Round 7
// 229.966 us; speedup vs baseline: 4.1938x; 1.1402x over previous
//
#include <hip/hip_runtime.h>
#include <math.h>

#define B_  2
#define L_  2048
#define DM  1024
#define DI  2048
#define DR  64
#define N_  16
#define K_  4
#define NROW (B_*L_)      // 4096
#define CH  64
#define NCH (L_/CH)       // 32
#define KS  8             // split-K factor for GEMM2

typedef __attribute__((ext_vector_type(8))) __bf16 bf16x8;
typedef __attribute__((ext_vector_type(4))) float f32x4;

__device__ __forceinline__ float silu_f(float x) { return x / (1.0f + __expf(-x)); }

// branch-free softplus from native v_exp_f32 / v_log_f32 only (no log1pf libcall)
__device__ __forceinline__ float softplus_f(float v) {
    return fmaxf(v, 0.0f) + __logf(1.0f + __expf(-fabsf(v)));
}

__device__ __forceinline__ unsigned short f2bf(float f) {
    unsigned u = __float_as_uint(f);
    unsigned r = (u + 0x7FFF + ((u >> 16) & 1)) >> 16;  // RNE
    return (unsigned short)r;
}
__device__ __forceinline__ float bf2f(unsigned short h) {
    return __uint_as_float(((unsigned)h) << 16);
}

__device__ __forceinline__ void gload_lds16(const void* g, void* l) {
    __builtin_amdgcn_global_load_lds(
        (const __attribute__((address_space(1))) void*)g,
        (__attribute__((address_space(3))) void*)l,
        16, 0, 0);
}

// ---------------- merged fp32 -> bf16 conversions (x, Win, Wout) ----------------
__global__ __launch_bounds__(256)
void convert_all_k(const float* __restrict__ x, const float* __restrict__ Win,
                   const float* __restrict__ Wout,
                   unsigned short* __restrict__ xb, unsigned short* __restrict__ wb,
                   unsigned short* __restrict__ wob)
{
    int i = blockIdx.x * 256 + threadIdx.x;
    const int n0 = (NROW*DM)/8, n1 = n0 + (2*DI*DM)/8, n2 = n1 + (DM*DI)/8;
    const float* src; unsigned short* dst;
    if (i < n0)      { src = x;    dst = xb; }
    else if (i < n1) { src = Win;  dst = wb;  i -= n0; }
    else if (i < n2) { src = Wout; dst = wob; i -= n1; }
    else return;
    const float4 a = *((const float4*)src + (size_t)i * 2);
    const float4 b = *((const float4*)src + (size_t)i * 2 + 1);
    union { unsigned short s[8]; uint4 v; } o;
    o.s[0] = f2bf(a.x); o.s[1] = f2bf(a.y); o.s[2] = f2bf(a.z); o.s[3] = f2bf(a.w);
    o.s[4] = f2bf(b.x); o.s[5] = f2bf(b.y); o.s[6] = f2bf(b.z); o.s[7] = f2bf(b.w);
    *(uint4*)(dst + (size_t)i * 8) = o.v;
}

// ---------------- merged fp32 -> split bf16 (Wx, Wdt) ----------------
__global__ __launch_bounds__(256)
void convert_split_all_k(const float* __restrict__ Wx, const float* __restrict__ Wdt,
                         unsigned short* __restrict__ wxh, unsigned short* __restrict__ wxl,
                         unsigned short* __restrict__ wdh, unsigned short* __restrict__ wdl)
{
    int i = blockIdx.x * 256 + threadIdx.x;
    const int n0 = 96*DI, n1 = n0 + DI*DR;
    const float* src; unsigned short *dh, *dl;
    if (i < n0)      { src = Wx;  dh = wxh; dl = wxl; }
    else if (i < n1) { src = Wdt; dh = wdh; dl = wdl; i -= n0; }
    else return;
    const float v = src[i];
    const unsigned short h = f2bf(v);
    dh[i] = h;
    dl[i] = f2bf(v - bf2f(h));
}

// ============ 256x256 bf16 MFMA NT GEMM, quad-buffered LDS, counted vmcnt ============
// C[MxN] = A[MxK] * B[NxK]^T.  M%256==0, N%256==0, K%32==0, K>=128.
// 512 threads = 8 waves (2M x 4N); per-wave output 128x64 (8x4 16x16 frags).
// LDS 128 KiB: A/B each 4 buffers of 256x32 bf16. Prefetch depth 3 tiles;
// ledger: vmcnt(8) mid-loop [never 0], vmcnt(4)/(0) last two tiles (R5 body —
// R6 phase-split was measured null; compiler already schedules ds_read↔MFMA).
// Swizzle: slot' = slot ^ ((row>>1)&3) via inverse-permuted GLOBAL source
// (linear gload_lds dest) + same XOR on read (rule 21). Bank-conflicts = 0 (R5 PMC).
__global__ __launch_bounds__(512, 2)
void gemm_bf16_256(const unsigned short* __restrict__ A,
                   const unsigned short* __restrict__ B,
                   float* __restrict__ C, int ldc, int K)
{
    __shared__ unsigned short lds[65536];   // 128 KiB
    const int tid = threadIdx.x;
    const int w = tid >> 6;          // wave 0..7
    const int l = tid & 63;
    const int wM = w >> 2;           // 0..1
    const int wN = w & 3;            // 0..3

    // XCD-aware block swizzle (grid sizes here are multiples of 8)
    const int nbx = gridDim.x;
    const int nwg = nbx * gridDim.y;
    int flat = blockIdx.y * nbx + blockIdx.x;
    flat = (flat & 7) * (nwg >> 3) + (flat >> 3);
    const int bn = (flat % nbx) * 256;
    const int bm = (flat / nbx) * 256;

    const int ksrc = (((l & 3) ^ ((l >> 3) & 3)) * 8);      // inverse-swizzled source k
    const int srow = w * 16 + (l >> 2);
    const unsigned short* a0 = A + (size_t)(bm + srow) * K + ksrc;
    const unsigned short* a1 = A + (size_t)(bm + 128 + srow) * K + ksrc;
    const unsigned short* b0 = B + (size_t)(bn + srow) * K + ksrc;
    const unsigned short* b1 = B + (size_t)(bn + 128 + srow) * K + ksrc;
    char* ldsc = (char*)lds;

    auto stage = [&](int p, int kof) {
        char* d = ldsc + p * 16384 + w * 1024;
        gload_lds16(a0 + kof, d);
        gload_lds16(a1 + kof, d + 8192);
        gload_lds16(b0 + kof, d + 65536);
        gload_lds16(b1 + kof, d + 65536 + 8192);
    };

    const int fr = l & 15, fq = l >> 4;
    const int slotr = fq ^ ((fr >> 1) & 3);
    int aoff[8], boff[4];
#pragma unroll
    for (int i = 0; i < 8; ++i) aoff[i] = (wM * 128 + i * 16 + fr) * 32 + slotr * 8;
#pragma unroll
    for (int j = 0; j < 4; ++j) boff[j] = (wN * 64 + j * 16 + fr) * 32 + slotr * 8;

    f32x4 acc[8][4] = {};
    const int NT = K >> 5;

    stage(0, 0);
    stage(1, 32);
    stage(2, 64);

    for (int t = 0; t < NT; ++t) {
        const int rem = NT - 1 - t;
        if (rem >= 2)      asm volatile("s_waitcnt vmcnt(8)" ::: "memory");
        else if (rem == 1) asm volatile("s_waitcnt vmcnt(4)" ::: "memory");
        else               asm volatile("s_waitcnt vmcnt(0)" ::: "memory");
        __builtin_amdgcn_s_barrier();
        __builtin_amdgcn_sched_barrier(0);

        if (t + 3 < NT) stage((t + 3) & 3, (t + 3) * 32);

        const unsigned short* Ab = lds + (t & 3) * 8192;
        const unsigned short* Bb = lds + 32768 + (t & 3) * 8192;
        bf16x8 af[8], bfr[4];
#pragma unroll
        for (int i = 0; i < 8; ++i) af[i] = *(const bf16x8*)(Ab + aoff[i]);
#pragma unroll
        for (int j = 0; j < 4; ++j) bfr[j] = *(const bf16x8*)(Bb + boff[j]);

        __builtin_amdgcn_s_setprio(1);
#pragma unroll
        for (int i = 0; i < 8; ++i)
#pragma unroll
            for (int j = 0; j < 4; ++j)
                acc[i][j] = __builtin_amdgcn_mfma_f32_16x16x32_bf16(af[i], bfr[j], acc[i][j], 0, 0, 0);
        __builtin_amdgcn_s_setprio(0);
    }

#pragma unroll
    for (int i = 0; i < 8; ++i)
#pragma unroll
        for (int j = 0; j < 4; ++j)
#pragma unroll
            for (int r = 0; r < 4; ++r) {
                const int row = bm + wM * 128 + i * 16 + fq * 4 + r;
                const int col = bn + wN * 64 + j * 16 + fr;
                C[(size_t)row * ldc + col] = acc[i][j][r];
            }
}

// ============ 128x128 bf16 MFMA NT GEMM, same ledger, 4 waves, 2 blocks/CU ============
// For M*N too small to fill the chip with 256^2 tiles (GEMM4: 4Melem -> needs 128^2).
// 256 threads = 4 waves (2M x 2N); per-wave output 64x64 (4x4 frags, 16 MFMA/K32).
// LDS 64 KiB (quad-buffer A/B 128x32) -> 2 blocks/CU: two independent vmcnt
// pipelines per CU. Identical swizzle/ledger math as the 256^2 kernel.
__global__ __launch_bounds__(256, 2)
void gemm_bf16_128(const unsigned short* __restrict__ A,
                   const unsigned short* __restrict__ B,
                   float* __restrict__ C, int ldc, int K)
{
    __shared__ unsigned short lds[32768];   // 64 KiB
    const int tid = threadIdx.x;
    const int w = tid >> 6;          // wave 0..3
    const int l = tid & 63;
    const int wM = w >> 1;           // 0..1
    const int wN = w & 1;            // 0..1

    const int nbx = gridDim.x;
    const int nwg = nbx * gridDim.y;
    int flat = blockIdx.y * nbx + blockIdx.x;
    flat = (flat & 7) * (nwg >> 3) + (flat >> 3);
    const int bn = (flat % nbx) * 128;
    const int bm = (flat / nbx) * 128;

    const int ksrc = (((l & 3) ^ ((l >> 3) & 3)) * 8);
    const int srow = w * 16 + (l >> 2);   // 0..63
    const unsigned short* a0 = A + (size_t)(bm + srow) * K + ksrc;
    const unsigned short* a1 = A + (size_t)(bm + 64 + srow) * K + ksrc;
    const unsigned short* b0 = B + (size_t)(bn + srow) * K + ksrc;
    const unsigned short* b1 = B + (size_t)(bn + 64 + srow) * K + ksrc;
    char* ldsc = (char*)lds;

    auto stage = [&](int p, int kof) {
        char* d = ldsc + p * 8192 + w * 1024;
        gload_lds16(a0 + kof, d);
        gload_lds16(a1 + kof, d + 4096);
        gload_lds16(b0 + kof, d + 32768);
        gload_lds16(b1 + kof, d + 32768 + 4096);
    };

    const int fr = l & 15, fq = l >> 4;
    const int slotr = fq ^ ((fr >> 1) & 3);
    int aoff[4], boff[4];
#pragma unroll
    for (int i = 0; i < 4; ++i) aoff[i] = (wM * 64 + i * 16 + fr) * 32 + slotr * 8;
#pragma unroll
    for (int j = 0; j < 4; ++j) boff[j] = (wN * 64 + j * 16 + fr) * 32 + slotr * 8;

    f32x4 acc[4][4] = {};
    const int NT = K >> 5;

    stage(0, 0);
    stage(1, 32);
    stage(2, 64);

    for (int t = 0; t < NT; ++t) {
        const int rem = NT - 1 - t;
        if (rem >= 2)      asm volatile("s_waitcnt vmcnt(8)" ::: "memory");
        else if (rem == 1) asm volatile("s_waitcnt vmcnt(4)" ::: "memory");
        else               asm volatile("s_waitcnt vmcnt(0)" ::: "memory");
        __builtin_amdgcn_s_barrier();
        __builtin_amdgcn_sched_barrier(0);

        if (t + 3 < NT) stage((t + 3) & 3, (t + 3) * 32);

        const unsigned short* Ab = lds + (t & 3) * 4096;
        const unsigned short* Bb = lds + 16384 + (t & 3) * 4096;
        bf16x8 af[4], bfr[4];
#pragma unroll
        for (int i = 0; i < 4; ++i) af[i] = *(const bf16x8*)(Ab + aoff[i]);
#pragma unroll
        for (int j = 0; j < 4; ++j) bfr[j] = *(const bf16x8*)(Bb + boff[j]);

        __builtin_amdgcn_s_setprio(1);
#pragma unroll
        for (int i = 0; i < 4; ++i)
#pragma unroll
            for (int j = 0; j < 4; ++j)
                acc[i][j] = __builtin_amdgcn_mfma_f32_16x16x32_bf16(af[i], bfr[j], acc[i][j], 0, 0, 0);
        __builtin_amdgcn_s_setprio(0);
    }

#pragma unroll
    for (int i = 0; i < 4; ++i)
#pragma unroll
        for (int j = 0; j < 4; ++j)
#pragma unroll
            for (int r = 0; r < 4; ++r) {
                const int row = bm + wM * 64 + i * 16 + fq * 4 + r;
                const int col = bn + wN * 64 + j * 16 + fr;
                C[(size_t)row * ldc + col] = acc[i][j][r];
            }
}

// ---------------- GEMM2 split-K: part[ks] += u[64rows x 256k] @ Wx^T (96 cols) --------
__global__ __launch_bounds__(256)
void gemm2_splitk(const unsigned short* __restrict__ uh, const unsigned short* __restrict__ ul,
                  const unsigned short* __restrict__ wxh, const unsigned short* __restrict__ wxl,
                  float* __restrict__ part)
{
    __shared__ unsigned short Ah[64 * 32], Al[64 * 32];
    __shared__ unsigned short Bh[96 * 32], Bl[96 * 32];
    const int tid = threadIdx.x;
    const int w = tid >> 6, l = tid & 63;
    const int ks = blockIdx.x;
    const int bm = blockIdx.y * 64;
    const int kbase = ks * (DI / KS);
    const int srow = l >> 2;
    const int skel = (l & 3) * 8;
    const int kk = (l >> 4) * 8, fr = l & 15, fq = l >> 4;

    f32x4 acc[6] = {};
    for (int k0 = 0; k0 < DI / KS; k0 += 32) {
        const int kg = kbase + k0;
        gload_lds16(uh  + (size_t)(bm + w * 16 + srow) * DI + kg + skel, &Ah[(w * 16) * 32]);
        gload_lds16(ul  + (size_t)(bm + w * 16 + srow) * DI + kg + skel, &Al[(w * 16) * 32]);
        gload_lds16(wxh + (size_t)(w * 16 + srow) * DI + kg + skel, &Bh[(w * 16) * 32]);
        gload_lds16(wxl + (size_t)(w * 16 + srow) * DI + kg + skel, &Bl[(w * 16) * 32]);
        if (w < 2) {
            gload_lds16(wxh + (size_t)(64 + w * 16 + srow) * DI + kg + skel, &Bh[(64 + w * 16) * 32]);
            gload_lds16(wxl + (size_t)(64 + w * 16 + srow) * DI + kg + skel, &Bl[(64 + w * 16) * 32]);
        }
        __syncthreads();
        const bf16x8 ah  = *(const bf16x8*)&Ah[(w * 16 + fr) * 32 + kk];
        const bf16x8 al2 = *(const bf16x8*)&Al[(w * 16 + fr) * 32 + kk];
#pragma unroll
        for (int j = 0; j < 6; ++j) {
            const bf16x8 bh  = *(const bf16x8*)&Bh[(j * 16 + fr) * 32 + kk];
            const bf16x8 bl2 = *(const bf16x8*)&Bl[(j * 16 + fr) * 32 + kk];
            acc[j] = __builtin_amdgcn_mfma_f32_16x16x32_bf16(ah,  bh,  acc[j], 0, 0, 0);
            acc[j] = __builtin_amdgcn_mfma_f32_16x16x32_bf16(ah,  bl2, acc[j], 0, 0, 0);
            acc[j] = __builtin_amdgcn_mfma_f32_16x16x32_bf16(al2, bh,  acc[j], 0, 0, 0);
        }
        __syncthreads();
    }
    float* p = part + (size_t)ks * (NROW * 96);
#pragma unroll
    for (int j = 0; j < 6; ++j)
#pragma unroll
        for (int r = 0; r < 4; ++r)
            p[(size_t)(bm + w * 16 + fq * 4 + r) * 96 + j * 16 + fr] = acc[j][r];
}

// ---------------- GEMM2 reduce: dbc = sum(part), dr -> split bf16 ----------------
__global__ __launch_bounds__(256)
void gemm2_reduce(const float* __restrict__ part, float* __restrict__ dbc,
                  unsigned short* __restrict__ drh, unsigned short* __restrict__ drl)
{
    const int idx = blockIdx.x * 256 + threadIdx.x;
    float s = 0.f;
#pragma unroll
    for (int ks = 0; ks < KS; ++ks) s += part[(size_t)ks * (NROW * 96) + idx];
    dbc[idx] = s;
    const int col = idx % 96;
    if (col < DR) {
        const int row = idx / 96;
        const unsigned short h = f2bf(s);
        drh[(size_t)row * DR + col] = h;
        drl[(size_t)row * DR + col] = f2bf(s - bf2f(h));
    }
}

// ---------------- GEMM3: delta = softplus(dr @ Wdt^T + bdt), split precision -------
__global__ __launch_bounds__(256)
void gemm3_delta(const unsigned short* __restrict__ Agh, const unsigned short* __restrict__ Agl,
                 const unsigned short* __restrict__ Bgh, const unsigned short* __restrict__ Bgl,
                 const float* __restrict__ bdt, float* __restrict__ delta)
{
    __shared__ unsigned short Ah[128 * 32], Al[128 * 32];
    __shared__ unsigned short Bh[128 * 32], Bl[128 * 32];
    const int tid = threadIdx.x;
    const int w = tid >> 6, l = tid & 63;
    const int bm = blockIdx.y * 128;
    const int bn = blockIdx.x * 128;
    const int wm = (w >> 1) * 64, wn = (w & 1) * 64;
    const int srow = w * 16 + (l >> 2);
    const int skel = (l & 3) * 8;
    const int kk = (l >> 4) * 8, fr = l & 15, fq = l >> 4;

    f32x4 acc[4][4] = {};
    for (int k0 = 0; k0 < DR; k0 += 32) {
        gload_lds16(Agh + (size_t)(bm + srow) * DR + k0 + skel,      &Ah[(w * 16) * 32]);
        gload_lds16(Agh + (size_t)(bm + 64 + srow) * DR + k0 + skel, &Ah[(64 + w * 16) * 32]);
        gload_lds16(Agl + (size_t)(bm + srow) * DR + k0 + skel,      &Al[(w * 16) * 32]);
        gload_lds16(Agl + (size_t)(bm + 64 + srow) * DR + k0 + skel, &Al[(64 + w * 16) * 32]);
        gload_lds16(Bgh + (size_t)(bn + srow) * DR + k0 + skel,      &Bh[(w * 16) * 32]);
        gload_lds16(Bgh + (size_t)(bn + 64 + srow) * DR + k0 + skel, &Bh[(64 + w * 16) * 32]);
        gload_lds16(Bgl + (size_t)(bn + srow) * DR + k0 + skel,      &Bl[(w * 16) * 32]);
        gload_lds16(Bgl + (size_t)(bn + 64 + srow) * DR + k0 + skel, &Bl[(64 + w * 16) * 32]);
        __syncthreads();
        bf16x8 ah[4], al2[4], bh[4], bl2[4];
#pragma unroll
        for (int i = 0; i < 4; ++i) {
            ah[i]  = *(const bf16x8*)&Ah[(wm + i * 16 + fr) * 32 + kk];
            al2[i] = *(const bf16x8*)&Al[(wm + i * 16 + fr) * 32 + kk];
        }
#pragma unroll
        for (int j = 0; j < 4; ++j) {
            bh[j]  = *(const bf16x8*)&Bh[(wn + j * 16 + fr) * 32 + kk];
            bl2[j] = *(const bf16x8*)&Bl[(wn + j * 16 + fr) * 32 + kk];
        }
#pragma unroll
        for (int i = 0; i < 4; ++i)
#pragma unroll
            for (int j = 0; j < 4; ++j) {
                acc[i][j] = __builtin_amdgcn_mfma_f32_16x16x32_bf16(ah[i],  bh[j],  acc[i][j], 0, 0, 0);
                acc[i][j] = __builtin_amdgcn_mfma_f32_16x16x32_bf16(ah[i],  bl2[j], acc[i][j], 0, 0, 0);
                acc[i][j] = __builtin_amdgcn_mfma_f32_16x16x32_bf16(al2[i], bh[j],  acc[i][j], 0, 0, 0);
            }
        __syncthreads();
    }
#pragma unroll
    for (int i = 0; i < 4; ++i)
#pragma unroll
        for (int j = 0; j < 4; ++j)
#pragma unroll
            for (int r = 0; r < 4; ++r) {
                const int row = bm + wm + i * 16 + fq * 4 + r;
                const int col = bn + wn + j * 16 + fr;
                delta[(size_t)row * DI + col] = softplus_f(acc[i][j][r] + bdt[col]);
            }
}

// ---------------- causal depthwise conv (K=4) + SiLU -> u split bf16 ----------------
__global__ __launch_bounds__(256)
void conv_silu_k(const float* __restrict__ xz, const float* __restrict__ cw,
                 const float* __restrict__ cb,
                 unsigned short* __restrict__ uh, unsigned short* __restrict__ ul)
{
    const size_t idx = (size_t)blockIdx.x * 256 + threadIdx.x;
    const int c = (int)(idx & (DI - 1));
    const size_t bl = idx >> 11;
    const int l = (int)(bl & (L_ - 1));
    const float4 w = *(const float4*)(cw + (size_t)c * 4);
    const float wk[4] = {w.x, w.y, w.z, w.w};
    float s = cb[c];
#pragma unroll
    for (int k = 0; k < 4; ++k) {
        const int t = l - 3 + k;
        if (t >= 0) s += xz[(bl - 3 + k) * (size_t)(2*DI) + c] * wk[k];
    }
    const float v = silu_f(s);
    const unsigned short h = f2bf(v);
    uh[idx] = h;
    ul[idx] = f2bf(v - bf2f(h));
}

// ---------------- selective scan: phase 1 ----------------
__global__ __launch_bounds__(256)
void scan_phase1(const float* __restrict__ delta,
                 const unsigned short* __restrict__ uh, const unsigned short* __restrict__ ul,
                 const float* __restrict__ dbc, const float* __restrict__ A_log,
                 float* __restrict__ Aprod, float* __restrict__ hfin)
{
    __shared__ float Bs[CH][N_];
    const int tid = threadIdx.x;
    const int d  = blockIdx.x * 256 + tid;
    const int ck = blockIdx.y;
    const int b  = blockIdx.z;
    const int l0 = ck * CH;
    for (int e = tid; e < CH * N_; e += 256) {
        const int lo = e >> 4, n = e & 15;
        Bs[lo][n] = dbc[((size_t)(b*L_ + l0 + lo)) * 96 + 64 + n];
    }
    __syncthreads();
    float An[N_], h[N_], P[N_];
#pragma unroll
    for (int n = 0; n < N_; ++n) {
        An[n] = -__expf(A_log[(size_t)d * N_ + n]);
        h[n] = 0.f; P[n] = 1.f;
    }
    size_t base = ((size_t)(b*L_ + l0)) * DI + d;
    for (int lo = 0; lo < CH; ++lo) {
        const float dl = delta[base];
        const float uu = bf2f(uh[base]) + bf2f(ul[base]);
        base += DI;
        const float du = dl * uu;
#pragma unroll
        for (int n = 0; n < N_; ++n) {
            const float da = __expf(dl * An[n]);
            h[n] = fmaf(da, h[n], du * Bs[lo][n]);
            P[n] *= da;
        }
    }
    const size_t o = (((size_t)(b*NCH + ck) * DI) + d) * N_;
#pragma unroll
    for (int n = 0; n < N_; n += 4) {
        *(float4*)(Aprod + o + n) = make_float4(P[n], P[n+1], P[n+2], P[n+3]);
        *(float4*)(hfin  + o + n) = make_float4(h[n], h[n+1], h[n+2], h[n+3]);
    }
}

// ---------------- selective scan: phase 2 (hinit MAY ALIAS Aprod: load-before-store) ----
__global__ __launch_bounds__(256)
void scan_phase2(const float* Aprod, const float* __restrict__ hfin, float* hinit)
{
    const size_t idx = (size_t)blockIdx.x * 256 + threadIdx.x;
    const int b = (idx >= (size_t)DI * N_) ? 1 : 0;
    const size_t dn = idx - (size_t)b * DI * N_;
    float h = 0.f;
    for (int c = 0; c < NCH; ++c) {
        const size_t o = ((size_t)(b*NCH + c) * DI) * N_ + dn;
        const float a = Aprod[o];
        const float f = hfin[o];
        hinit[o] = h;
        h = fmaf(a, h, f);
    }
}

// ---------------- selective scan: phase 3 (replay + y + gate -> bf16 g) ----------------
__global__ __launch_bounds__(256)
void scan_phase3(const float* __restrict__ delta,
                 const unsigned short* __restrict__ uh, const unsigned short* __restrict__ ul,
                 const float* __restrict__ dbc, const float* __restrict__ A_log,
                 const float* __restrict__ hinit, const float* __restrict__ Dp,
                 const float* __restrict__ xz, unsigned short* __restrict__ gb)
{
    __shared__ float Bs[CH][N_];
    __shared__ float Cs[CH][N_];
    const int tid = threadIdx.x;
    const int d  = blockIdx.x * 256 + tid;
    const int ck = blockIdx.y;
    const int b  = blockIdx.z;
    const int l0 = ck * CH;
    for (int e = tid; e < CH * N_; e += 256) {
        const int lo = e >> 4, n = e & 15;
        const size_t r = ((size_t)(b*L_ + l0 + lo)) * 96;
        Bs[lo][n] = dbc[r + 64 + n];
        Cs[lo][n] = dbc[r + 80 + n];
    }
    __syncthreads();
    float An[N_], h[N_];
    const size_t ho = (((size_t)(b*NCH + ck) * DI) + d) * N_;
#pragma unroll
    for (int n = 0; n < N_; n += 4) {
        const float4 hv = *(const float4*)(hinit + ho + n);
        h[n] = hv.x; h[n+1] = hv.y; h[n+2] = hv.z; h[n+3] = hv.w;
    }
#pragma unroll
    for (int n = 0; n < N_; ++n)
        An[n] = -__expf(A_log[(size_t)d * N_ + n]);
    const float dp = Dp[d];
    size_t base  = ((size_t)(b*L_ + l0)) * DI + d;
    size_t zbase = ((size_t)(b*L_ + l0)) * (2*DI) + DI + d;
    size_t gidx  = ((size_t)(b*L_ + l0)) * DI + d;
    for (int lo = 0; lo < CH; ++lo) {
        const float dl = delta[base];
        const float uu = bf2f(uh[base]) + bf2f(ul[base]);
        base += DI;
        const float du = dl * uu;
        float y = 0.f;
#pragma unroll
        for (int n = 0; n < N_; ++n) {
            const float da = __expf(dl * An[n]);
            h[n] = fmaf(da, h[n], du * Bs[lo][n]);
            y = fmaf(h[n], Cs[lo][n], y);
        }
        y = fmaf(dp, uu, y);
        const float zz = xz[zbase]; zbase += 2*DI;
        gb[gidx] = f2bf(y * silu_f(zz)); gidx += DI;
    }
}

extern "C" void kernel_launch(void* const* d_in, const int* in_sizes, int n_in,
                              void* d_out, int out_size, void* d_ws, size_t ws_size,
                              hipStream_t stream)
{
    const float* x     = (const float*)d_in[0];
    const float* Win   = (const float*)d_in[1];
    const float* cw    = (const float*)d_in[2];
    const float* cb    = (const float*)d_in[3];
    const float* Wx    = (const float*)d_in[4];
    const float* Wdt   = (const float*)d_in[5];
    const float* bdt   = (const float*)d_in[6];
    const float* A_log = (const float*)d_in[7];
    const float* Dp    = (const float*)d_in[8];
    const float* Wout  = (const float*)d_in[9];
    float* out = (float*)d_out;

    float* ws    = (float*)d_ws;
    float* xz    = ws;                                    // NROW*2*DI f32
    float* delta = xz    + (size_t)NROW * 2 * DI;         // NROW*DI f32
    float* dbc   = delta + (size_t)NROW * DI;             // NROW*96 f32
    float* Aprod = dbc   + (size_t)NROW * 96;             // B_*NCH*DI*N_ f32
    float* hfin  = Aprod + (size_t)B_ * NCH * DI * N_;    // B_*NCH*DI*N_ f32
    float* hinit = Aprod;                                 // ALIASES Aprod (phase2 load-before-store)
    unsigned short* uh  = (unsigned short*)(hfin + (size_t)B_ * NCH * DI * N_);  // NROW*DI
    unsigned short* ul  = uh  + (size_t)NROW * DI;
    unsigned short* xb  = ul  + (size_t)NROW * DI;        // NROW*DM (dead after GEMM1)
    unsigned short* wb  = xb  + (size_t)NROW * DM;        // 2DI*DM  (dead after GEMM1)
    unsigned short* wob = wb  + (size_t)(2*DI) * DM;      // DM*DI
    unsigned short* gb  = wob + (size_t)DM * DI;          // NROW*DI
    unsigned short* wxh = gb  + (size_t)NROW * DI;        // 96*DI
    unsigned short* wxl = wxh + (size_t)96 * DI;
    unsigned short* wdh = wxl + (size_t)96 * DI;          // DI*DR
    unsigned short* wdl = wdh + (size_t)DI * DR;
    float* part = (float*)xb;                             // KS*NROW*96 f32 (dead xb/wb region)
    unsigned short* drh = (unsigned short*)(part + (size_t)KS * NROW * 96);  // NROW*DR
    unsigned short* drl = drh + (size_t)NROW * DR;

    const dim3 blk(256);

    // 0) conversions (merged: 2 launches)
    convert_all_k<<<dim3(5120), blk, 0, stream>>>(x, Win, Wout, xb, wb, wob);
    convert_split_all_k<<<dim3(1280), blk, 0, stream>>>(Wx, Wdt, wxh, wxl, wdh, wdl);
    // 1) xz = x @ Win^T   (4096 x 4096 x 1024, 256^2 pipelined MFMA, 256 blocks)
    gemm_bf16_256<<<dim3((2*DI)/256, NROW/256), dim3(512), 0, stream>>>(xb, wb, xz, 2*DI, DM);
    // 2) u = silu(conv1d(xin)) -> split bf16
    conv_silu_k<<<dim3((NROW * DI) / 256), blk, 0, stream>>>(xz, cw, cb, uh, ul);
    // 3) dbc = u @ Wx^T   (split-K bf16 MFMA + reduce)
    gemm2_splitk<<<dim3(KS, NROW/64), blk, 0, stream>>>(uh, ul, wxh, wxl, part);
    gemm2_reduce<<<dim3((NROW*96)/256), blk, 0, stream>>>(part, dbc, drh, drl);
    // 4) delta = softplus(dr @ Wdt^T + bdt)   (split bf16 MFMA)
    gemm3_delta<<<dim3(DI/128, NROW/128), blk, 0, stream>>>(drh, drl, wdh, wdl, bdt, delta);
    // 5-7) chunked selective scan
    scan_phase1<<<dim3(DI/256, NCH, B_), blk, 0, stream>>>(delta, uh, ul, dbc, A_log, Aprod, hfin);
    scan_phase2<<<dim3((B_*DI*N_)/256), blk, 0, stream>>>(Aprod, hfin, hinit);
    scan_phase3<<<dim3(DI/256, NCH, B_), blk, 0, stream>>>(delta, uh, ul, dbc, A_log, hinit, Dp, xz, gb);
    // 8) out = g @ Wout^T  (4096 x 1024 x 2048, 128^2 pipelined MFMA, 256 blocks, 2/CU)
    gemm_bf16_128<<<dim3(DM/128, NROW/128), dim3(256), 0, stream>>>(gb, wob, out, DM, DI);
}